// Round 23
// baseline (94.522 us; speedup 1.0000x reference)
//
#include <hip/hip_runtime.h>

#define T_FRAMES 1001
#define MEL_STRIDE 1008
#define PG_STRIDE 272   // u16 per P row (264 + pad)

// ws float offsets
#define OFF_WIN 0          // [416] f32
#define OFF_BG  1696       // u16[13 ktile][16384] twiddles, chunked (106496 f)
#define OFF_FBG 108192     // u16[64 mel][264] (8448 f)
#define OFF_DCT16 120000   // f16[32 k][64 m] DCT^T, rows 20..31 zero (1024 f)
#define OFF_PG  121100     // u16 [64 b][1024 fr][272] power spectrum (8912896 f)
#define OFF_MEL 9034000    // u16(bf16) [4096][1008]

typedef unsigned int u32;
typedef unsigned short u16;
typedef __attribute__((ext_vector_type(8))) short bf16x8;
typedef __attribute__((ext_vector_type(8))) _Float16 f16x8;
typedef __attribute__((ext_vector_type(4))) float f32x4;

__device__ __forceinline__ u16 f2bf(float f) {
  u32 u = __float_as_uint(f);
  u32 r = (u + 0x7FFFu + ((u >> 16) & 1u)) >> 16;
  return (u16)r;
}

__device__ __forceinline__ float bf2f(u32 h) {  // low 16 bits = bf16
  return __uint_as_float(h << 16);
}

__device__ __forceinline__ int reflect_idx(int g) {
  g = (g < 0) ? -g : g;
  g = (g >= 160000) ? (319998 - g) : g;
  return g;
}

__global__ __launch_bounds__(256) void k_init(float* __restrict__ ws) {
  float* win = ws + OFF_WIN;
  u16* bg = (u16*)(ws + OFF_BG);
  u16* fbg = (u16*)(ws + OFF_FBG);
  _Float16* dct16 = (_Float16*)(ws + OFF_DCT16);
  const float W = 6.28318530717958647692f / 400.0f;
  int tid = blockIdx.x * 256 + threadIdx.x;
  int stride = gridDim.x * 256;
  for (int i = tid; i < 416; i += stride)
    win[i] = (i < 400) ? (0.5f - 0.5f * cosf((float)i * W)) : 0.0f;
  for (int i = tid; i < 32 * 64; i += stride) {
    int k = i >> 6, m = i & 63;
    float v = 0.0f;
    if (k < 20) {
      v = cosf(3.14159265358979323846f / 64.0f * ((float)m + 0.5f) * (float)k) * sqrtf(2.0f / 64.0f);
      if (k == 0) v *= 0.70710678118654752440f;
    }
    dct16[i] = (_Float16)v;
  }
  // twiddles, chunked: u16 index = kt*16384 + g*512 + khalf*128 + c15*8 + e
  for (int i = tid; i < 13 * 16384; i += stride) {
    int kt = i >> 14;
    int r = i & 16383;
    int g = r >> 9;
    int khalf = (r >> 7) & 3;
    int c15 = (r >> 3) & 15;
    int e = r & 7;
    int col = g * 16 + c15;
    int n = kt * 32 + khalf * 8 + e;
    int bin = ((col >> 5) << 4) | (col & 15);
    int type = (col >> 4) & 1;
    float v = 0.0f;
    if (n < 400 && bin <= 200) {
      float a = (float)((n * bin) % 400) * W;
      v = type ? -sinf(a) : cosf(a);
    }
    bg[i] = f2bf(v);
  }
  // mel filterbank [mel][264], zero past bin 200
  for (int i = tid; i < 64 * 264; i += stride) {
    int m = i / 264, f = i % 264;
    float v = 0.0f;
    if (f <= 200) {
      float freq = 40.0f * (float)f;
      float m_max = 2595.0f * log10f(1.0f + 8000.0f / 700.0f);
      float ms = m_max / 65.0f;
      float fp0 = 700.0f * (powf(10.0f, (float)(m)     * ms / 2595.0f) - 1.0f);
      float fp1 = 700.0f * (powf(10.0f, (float)(m + 1) * ms / 2595.0f) - 1.0f);
      float fp2 = 700.0f * (powf(10.0f, (float)(m + 2) * ms / 2595.0f) - 1.0f);
      float dn = (freq - fp0) / (fp1 - fp0);
      float up = (fp2 - freq) / (fp2 - fp1);
      v = fmaxf(0.0f, fminf(dn, up));
    }
    fbg[i] = f2bf(v);
  }
}

// k_dft: one block = 128 frames of one batch row; 512 threads = 8 waves.
// A-build -> barrier -> GEMM1 (1M x 8N, barrier-free, dead-col-trimmed) ->
// P = re^2+im^2 stored bf16 DIRECT TO GLOBAL Pg (+ zero bins 208..263).
// Only ONE barrier in the whole kernel; no epilogue GEMMs (moved to k_post).
__global__ __launch_bounds__(512, 2) void k_dft(const float* __restrict__ wav,
                                                const float* __restrict__ ws,
                                                u16* __restrict__ Pg) {
  extern __shared__ char sm[];  // A: [13 kt][8192 B]
  const char* Bg = (const char*)(ws + OFF_BG);
  const float* win = ws + OFF_WIN;
  int tid = threadIdx.x, wid = tid >> 6, lane = tid & 63;
  int bx = blockIdx.x, b = blockIdx.y;
  const float* wv = wav + (size_t)b * 160000;
  u16* Pt = Pg + ((size_t)b * 1024 + bx * 128) * PG_STRIDE;  // this block's tile

  // ---- A build, all 13 ktiles: 4 lanes per frame row (coalesced reads) ----
  {
    int kq = tid & 3, rowq = tid >> 2;
    int frame = bx * 128 + rowq;
    bool fvalid = (frame <= 1000);
#pragma unroll 4
    for (int kt = 0; kt < 13; ++kt) {
      int n0 = kt * 32 + kq * 8;
      int g0 = frame * 160 + n0 - 200;
      float ax[8];
      if (fvalid) {
        if (g0 >= 0 && g0 + 7 < 160000) {
          float4 u = *(const float4*)&wv[g0];
          float4 v = *(const float4*)&wv[g0 + 4];
          ax[0] = u.x; ax[1] = u.y; ax[2] = u.z; ax[3] = u.w;
          ax[4] = v.x; ax[5] = v.y; ax[6] = v.z; ax[7] = v.w;
        } else {
#pragma unroll
          for (int e = 0; e < 8; ++e) ax[e] = wv[reflect_idx(g0 + e)];
        }
      } else {
#pragma unroll
        for (int e = 0; e < 8; ++e) ax[e] = 0.0f;
      }
      float4 w0 = *(const float4*)&win[n0];
      float4 w1 = *(const float4*)&win[n0 + 4];
      uint4 pk;
      pk.x = (u32)f2bf(ax[0] * w0.x) | ((u32)f2bf(ax[1] * w0.y) << 16);
      pk.y = (u32)f2bf(ax[2] * w0.z) | ((u32)f2bf(ax[3] * w0.w) << 16);
      pk.z = (u32)f2bf(ax[4] * w1.x) | ((u32)f2bf(ax[5] * w1.y) << 16);
      pk.w = (u32)f2bf(ax[6] * w1.z) | ((u32)f2bf(ax[7] * w1.w) << 16);
      *(uint4*)(sm + kt * 8192 + kq * 2048 + rowq * 16) = pk;
    }
  }
  __syncthreads();

  // ---- GEMM1: barrier-free K-loop, 1M x 8N (13 bingroups, bins 0..207) ----
  int NG = (wid < 5) ? 2 : 1;
  int GB = (wid < 5) ? wid * 2 : wid + 5;

  f32x4 acc[8][4];
  const f32x4 zf = {0.0f, 0.0f, 0.0f, 0.0f};
#pragma unroll
  for (int mi = 0; mi < 8; ++mi)
#pragma unroll
    for (int j = 0; j < 4; ++j) acc[mi][j] = zf;

#pragma unroll
  for (int kt = 0; kt < 13; ++kt) {
    bf16x8 bfr[4];
    bfr[0] = *(const bf16x8*)(Bg + kt * 32768 + (2 * GB) * 1024 + lane * 16);
    bfr[1] = *(const bf16x8*)(Bg + kt * 32768 + (2 * GB + 1) * 1024 + lane * 16);
    if (NG == 2) {
      bfr[2] = *(const bf16x8*)(Bg + kt * 32768 + (2 * GB + 2) * 1024 + lane * 16);
      bfr[3] = *(const bf16x8*)(Bg + kt * 32768 + (2 * GB + 3) * 1024 + lane * 16);
    }
#pragma unroll
    for (int mi = 0; mi < 8; ++mi) {
      bf16x8 af = *(const bf16x8*)(sm + kt * 8192 + (lane >> 4) * 2048 +
                                   (mi * 16 + (lane & 15)) * 16);
      acc[mi][0] = __builtin_amdgcn_mfma_f32_16x16x32_bf16(af, bfr[0], acc[mi][0], 0, 0, 0);
      acc[mi][1] = __builtin_amdgcn_mfma_f32_16x16x32_bf16(af, bfr[1], acc[mi][1], 0, 0, 0);
      if (NG == 2) {
        acc[mi][2] = __builtin_amdgcn_mfma_f32_16x16x32_bf16(af, bfr[2], acc[mi][2], 0, 0, 0);
        acc[mi][3] = __builtin_amdgcn_mfma_f32_16x16x32_bf16(af, bfr[3], acc[mi][3], 0, 0, 0);
      }
    }
  }

  // ---- P = re^2+im^2 (bf16) direct to global; zero dead bins 208..263 ----
#pragma unroll
  for (int j = 0; j < 2; ++j) {
    if (j < NG) {
      int bin = (GB + j) * 16 + (lane & 15);
#pragma unroll
      for (int mi = 0; mi < 8; ++mi)
#pragma unroll
        for (int r = 0; r < 4; ++r) {
          int row = mi * 16 + (lane >> 4) * 4 + r;
          float re = acc[mi][2 * j][r], im = acc[mi][2 * j + 1][r];
          Pt[row * PG_STRIDE + bin] = f2bf(re * re + im * im);
        }
    }
  }
  {
    u32* Pt32 = (u32*)Pt;  // zero bins 208..263 (u32 cols 104..131), 128 rows
    for (int i = tid; i < 128 * 28; i += 512) {
      int row = i / 28, c = i - row * 28;
      Pt32[row * (PG_STRIDE / 2) + 104 + c] = 0;
    }
  }
}

// k_post: GEMM2 (mel) + GEMM3 (MFCC), P fragments read per-lane from global.
// Small LDS (db only, 18.4 KB) + low VGPR -> multiple blocks/CU, overlaps well.
__global__ __launch_bounds__(512) void k_post(const float* __restrict__ ws,
                                              const u16* __restrict__ Pg,
                                              u16* __restrict__ mel,
                                              float* __restrict__ mfcc) {
  extern __shared__ char sm[];  // db: [128 t][72] f16
  const u16* FBg = (const u16*)(ws + OFF_FBG);               // [64 mel][264]
  const _Float16* DCTg = (const _Float16*)(ws + OFF_DCT16);  // [32 k][64 m]
  int tid = threadIdx.x, wid = tid >> 6, lane = tid & 63;
  int bx = blockIdx.x, b = blockIdx.y;
  const u16* Pt = Pg + ((size_t)b * 1024 + bx * 128) * PG_STRIDE;
  const f32x4 zf = {0.0f, 0.0f, 0.0f, 0.0f};

  // ---- GEMM2 (swapped): D[m][frame] = FB[m][bins] x P^T[bins][frame] ----
  f32x4 macc[4];
#pragma unroll
  for (int nf = 0; nf < 4; ++nf) macc[nf] = zf;
#pragma unroll
  for (int kt = 0; kt < 8; ++kt) {
    int krow = kt * 32 + (lane >> 4) * 8;
    bf16x8 pb = *(const bf16x8*)&Pt[(wid * 16 + (lane & 15)) * PG_STRIDE + krow];
#pragma unroll
    for (int nf = 0; nf < 4; ++nf) {
      bf16x8 fa = *(const bf16x8*)&FBg[(nf * 16 + (lane & 15)) * 264 + krow];
      macc[nf] = __builtin_amdgcn_mfma_f32_16x16x32_bf16(fa, pb, macc[nf], 0, 0, 0);
    }
  }

  // ---- mel direct store (bf16): D col = frame, row = m ----
  int t = bx * 128 + wid * 16 + (lane & 15);
  if (t <= 1000) {
#pragma unroll
    for (int nf = 0; nf < 4; ++nf)
#pragma unroll
      for (int r = 0; r < 4; ++r) {
        int m = nf * 16 + (lane >> 4) * 4 + r;
        mel[((size_t)b * 64 + m) * MEL_STRIDE + t] = f2bf(macc[nf][r]);
      }
  }

  // ---- GEMM3 (MFCC): db = 10log10(max(mel,1e-10)) -> f16 LDS (own rows,
  //      no barrier), D2[k][t] = DCT16[k][m] x db[t][m] ----
  _Float16* db = (_Float16*)sm;  // [128 t][72] f16
  {
    int tl = wid * 16 + (lane & 15);
#pragma unroll
    for (int nf = 0; nf < 4; ++nf)
#pragma unroll
      for (int r = 0; r < 4; ++r) {
        int m = nf * 16 + (lane >> 4) * 4 + r;
        float d = 10.0f * log10f(fmaxf(macc[nf][r], 1e-10f));
        db[tl * 72 + m] = (_Float16)d;
      }
    f32x4 mf0 = zf, mf1 = zf;
#pragma unroll
    for (int mkt = 0; mkt < 2; ++mkt) {
      int ms = mkt * 32 + (lane >> 4) * 8;
      f16x8 pb3 = *(const f16x8*)&db[(wid * 16 + (lane & 15)) * 72 + ms];
      f16x8 fa0 = *(const f16x8*)&DCTg[((lane & 15)) * 64 + ms];
      f16x8 fa1 = *(const f16x8*)&DCTg[(16 + (lane & 15)) * 64 + ms];
      mf0 = __builtin_amdgcn_mfma_f32_16x16x32_f16(fa0, pb3, mf0, 0, 0, 0);
      mf1 = __builtin_amdgcn_mfma_f32_16x16x32_f16(fa1, pb3, mf1, 0, 0, 0);
    }
    if (t <= 1000) {
#pragma unroll
      for (int r = 0; r < 4; ++r) {
        int k0 = (lane >> 4) * 4 + r;
        mfcc[((size_t)b * 20 + k0) * 1001 + t] = mf0[r];
        int k1 = 16 + (lane >> 4) * 4 + r;
        if (k1 < 20)
          mfcc[((size_t)b * 20 + k1) * 1001 + t] = mf1[r];
      }
    }
  }
}

// Wave-parallel EMA scan: one wave per (b,m) row, 16 t/lane (bf16 input).
__global__ __launch_bounds__(256) void k_ema(const u16* __restrict__ mel,
                                             float* __restrict__ outp) {
  int wid = threadIdx.x >> 6, lane = threadIdx.x & 63;
  int row = blockIdx.x * 4 + wid;  // 0..4095
  const u16* src = mel + (size_t)row * MEL_STRIDE + lane * 16;

  float x[16];
  if (lane < 63) {
    uint4 v0 = *(const uint4*)&src[0];
    uint4 v1 = *(const uint4*)&src[8];
    x[0] = bf2f(v0.x & 0xFFFF);  x[1] = bf2f(v0.x >> 16);
    x[2] = bf2f(v0.y & 0xFFFF);  x[3] = bf2f(v0.y >> 16);
    x[4] = bf2f(v0.z & 0xFFFF);  x[5] = bf2f(v0.z >> 16);
    x[6] = bf2f(v0.w & 0xFFFF);  x[7] = bf2f(v0.w >> 16);
    x[8] = bf2f(v1.x & 0xFFFF);  x[9] = bf2f(v1.x >> 16);
    x[10] = bf2f(v1.y & 0xFFFF); x[11] = bf2f(v1.y >> 16);
    x[12] = bf2f(v1.z & 0xFFFF); x[13] = bf2f(v1.z >> 16);
    x[14] = bf2f(v1.w & 0xFFFF); x[15] = bf2f(v1.w >> 16);
#pragma unroll
    for (int i = 0; i < 16; ++i)
      if (lane * 16 + i > 1000) x[i] = 0.0f;
  } else {
#pragma unroll
    for (int i = 0; i < 16; ++i) x[i] = 0.0f;
  }

  float B = 0.0f;
#pragma unroll
  for (int i = 0; i < 16; ++i) B = fmaf(0.98f, B, 0.02f * x[i]);
  float A = 1.0f;
#pragma unroll
  for (int i = 0; i < 16; ++i) A *= 0.98f;

#pragma unroll
  for (int d = 1; d < 64; d <<= 1) {
    float Ap = __shfl_up(A, d, 64);
    float Bp = __shfl_up(B, d, 64);
    if (lane >= d) {
      B = fmaf(A, Bp, B);
      A = A * Ap;
    }
  }
  float s = __shfl_up(B, 1, 64);
  if (lane == 0) s = 0.0f;

  float* dst = outp + (size_t)row * 1001 + lane * 16;
#pragma unroll
  for (int i = 0; i < 16; ++i) {
    s = fmaf(0.98f, s, 0.02f * x[i]);
    if (lane * 16 + i <= 1000) dst[i] = log1pf(x[i] / (s + 1e-6f));
  }
}

extern "C" void kernel_launch(void* const* d_in, const int* in_sizes, int n_in,
                              void* d_out, int out_size, void* d_ws, size_t ws_size,
                              hipStream_t stream) {
  const float* wav = (const float*)d_in[0];
  float* out = (float*)d_out;
  float* ws = (float*)d_ws;
  u16* Pg = (u16*)(ws + OFF_PG);
  u16* mel = (u16*)(ws + OFF_MEL);

  hipFuncSetAttribute(reinterpret_cast<const void*>(k_dft),
                      hipFuncAttributeMaxDynamicSharedMemorySize, 106496);
  hipFuncSetAttribute(reinterpret_cast<const void*>(k_post),
                      hipFuncAttributeMaxDynamicSharedMemorySize, 18432);

  hipLaunchKernelGGL(k_init, dim3(256), dim3(256), 0, stream, ws);
  hipLaunchKernelGGL(k_dft, dim3(8, 64), dim3(512), 106496, stream, wav, ws, Pg);
  hipLaunchKernelGGL(k_post, dim3(8, 64), dim3(512), 18432, stream, ws, Pg, mel,
                     out + 4100096);
  hipLaunchKernelGGL(k_ema, dim3(1024), dim3(256), 0, stream, mel, out);
}

// Round 24
// 85.715 us; speedup vs baseline: 1.1027x; 1.1027x over previous
//
#include <hip/hip_runtime.h>

#define T_FRAMES 1001
#define MEL_STRIDE 1008
#define P_STRIDE 268

// ws float offsets
#define OFF_WIN 0          // [416] f32
#define OFF_BG  1696       // u16[13 ktile][16384] twiddles, chunked (106496 f)
#define OFF_FBG 108192     // u16[64 mel][264] (8448 f)
#define OFF_DCT16 120000   // f16[32 k][64 m] DCT^T, rows 20..31 zero (1024 f)
#define OFF_MEL 13748128   // u16(bf16) [4096][1008]

typedef unsigned int u32;
typedef unsigned short u16;
typedef __attribute__((ext_vector_type(8))) short bf16x8;
typedef __attribute__((ext_vector_type(8))) _Float16 f16x8;
typedef __attribute__((ext_vector_type(4))) float f32x4;

__device__ __forceinline__ u16 f2bf(float f) {
  u32 u = __float_as_uint(f);
  u32 r = (u + 0x7FFFu + ((u >> 16) & 1u)) >> 16;
  return (u16)r;
}

__device__ __forceinline__ float bf2f(u32 h) {  // low 16 bits = bf16
  return __uint_as_float(h << 16);
}

__device__ __forceinline__ int reflect_idx(int g) {
  g = (g < 0) ? -g : g;
  g = (g >= 160000) ? (319998 - g) : g;
  return g;
}

__global__ __launch_bounds__(256) void k_init(float* __restrict__ ws) {
  float* win = ws + OFF_WIN;
  u16* bg = (u16*)(ws + OFF_BG);
  u16* fbg = (u16*)(ws + OFF_FBG);
  _Float16* dct16 = (_Float16*)(ws + OFF_DCT16);
  const float W = 6.28318530717958647692f / 400.0f;
  int tid = blockIdx.x * 256 + threadIdx.x;
  int stride = gridDim.x * 256;
  for (int i = tid; i < 416; i += stride)
    win[i] = (i < 400) ? (0.5f - 0.5f * cosf((float)i * W)) : 0.0f;
  // DCT^T in f16: [32 k-rows][64 m], rows >=20 zero (MFMA pad)
  for (int i = tid; i < 32 * 64; i += stride) {
    int k = i >> 6, m = i & 63;
    float v = 0.0f;
    if (k < 20) {
      v = cosf(3.14159265358979323846f / 64.0f * ((float)m + 0.5f) * (float)k) * sqrtf(2.0f / 64.0f);
      if (k == 0) v *= 0.70710678118654752440f;
    }
    dct16[i] = (_Float16)v;
  }
  // twiddles, chunked: u16 index = kt*16384 + g*512 + khalf*128 + c15*8 + e
  for (int i = tid; i < 13 * 16384; i += stride) {
    int kt = i >> 14;
    int r = i & 16383;
    int g = r >> 9;
    int khalf = (r >> 7) & 3;
    int c15 = (r >> 3) & 15;
    int e = r & 7;
    int col = g * 16 + c15;
    int n = kt * 32 + khalf * 8 + e;
    int bin = ((col >> 5) << 4) | (col & 15);
    int type = (col >> 4) & 1;
    float v = 0.0f;
    if (n < 400 && bin <= 200) {
      float a = (float)((n * bin) % 400) * W;
      v = type ? -sinf(a) : cosf(a);
    }
    bg[i] = f2bf(v);
  }
  // mel filterbank [mel][264], zero past bin 200
  for (int i = tid; i < 64 * 264; i += stride) {
    int m = i / 264, f = i % 264;
    float v = 0.0f;
    if (f <= 200) {
      float freq = 40.0f * (float)f;
      float m_max = 2595.0f * log10f(1.0f + 8000.0f / 700.0f);
      float ms = m_max / 65.0f;
      float fp0 = 700.0f * (powf(10.0f, (float)(m)     * ms / 2595.0f) - 1.0f);
      float fp1 = 700.0f * (powf(10.0f, (float)(m + 1) * ms / 2595.0f) - 1.0f);
      float fp2 = 700.0f * (powf(10.0f, (float)(m + 2) * ms / 2595.0f) - 1.0f);
      float dn = (freq - fp0) / (fp1 - fp0);
      float up = (fp2 - freq) / (fp2 - fp1);
      v = fmaxf(0.0f, fminf(dn, up));
    }
    fbg[i] = f2bf(v);
  }
}

// One block = 128 frames of one batch row; 512 threads = 8 waves.
// GEMM1: 1M x 8N, dead-column-trimmed, kt loop at unroll-2 (NOT fully
// unrolled: the 13x straight-line body left no registers for load hoisting —
// a rotated loop lets the scheduler pipeline iter k+1's B-loads under iter
// k's 32 MFMAs). GEMM2: mel (bf16). GEMM3: fused MFCC via f16 MFMA.
__global__ __launch_bounds__(512, 2) void k_gemm(const float* __restrict__ wav,
                                                 const float* __restrict__ ws,
                                                 u16* __restrict__ mel,
                                                 float* __restrict__ mfcc) {
  extern __shared__ char sm[];  // A: [13 kt][8192 B]; P overlays; db @69632
  const char* Bg = (const char*)(ws + OFF_BG);
  const u16* FBg = (const u16*)(ws + OFF_FBG);        // [64 mel][264]
  const _Float16* DCTg = (const _Float16*)(ws + OFF_DCT16);  // [32 k][64 m]
  const float* win = ws + OFF_WIN;
  int tid = threadIdx.x, wid = tid >> 6, lane = tid & 63;
  int bx = blockIdx.x, b = blockIdx.y;
  const float* wv = wav + (size_t)b * 160000;

  // ---- A build, all 13 ktiles: 4 lanes per frame row (coalesced reads) ----
  {
    int kq = tid & 3, rowq = tid >> 2;
    int frame = bx * 128 + rowq;
    bool fvalid = (frame <= 1000);
#pragma unroll 4
    for (int kt = 0; kt < 13; ++kt) {
      int n0 = kt * 32 + kq * 8;
      int g0 = frame * 160 + n0 - 200;
      float ax[8];
      if (fvalid) {
        if (g0 >= 0 && g0 + 7 < 160000) {
          float4 u = *(const float4*)&wv[g0];
          float4 v = *(const float4*)&wv[g0 + 4];
          ax[0] = u.x; ax[1] = u.y; ax[2] = u.z; ax[3] = u.w;
          ax[4] = v.x; ax[5] = v.y; ax[6] = v.z; ax[7] = v.w;
        } else {
#pragma unroll
          for (int e = 0; e < 8; ++e) ax[e] = wv[reflect_idx(g0 + e)];
        }
      } else {
#pragma unroll
        for (int e = 0; e < 8; ++e) ax[e] = 0.0f;
      }
      float4 w0 = *(const float4*)&win[n0];
      float4 w1 = *(const float4*)&win[n0 + 4];
      uint4 pk;
      pk.x = (u32)f2bf(ax[0] * w0.x) | ((u32)f2bf(ax[1] * w0.y) << 16);
      pk.y = (u32)f2bf(ax[2] * w0.z) | ((u32)f2bf(ax[3] * w0.w) << 16);
      pk.z = (u32)f2bf(ax[4] * w1.x) | ((u32)f2bf(ax[5] * w1.y) << 16);
      pk.w = (u32)f2bf(ax[6] * w1.z) | ((u32)f2bf(ax[7] * w1.w) << 16);
      *(uint4*)(sm + kt * 8192 + kq * 2048 + rowq * 16) = pk;
    }
  }
  __syncthreads();

  // ---- GEMM1: K-loop at unroll-2, 1M x 8N (13 bingroups, bins 0..207) ----
  int NG = (wid < 5) ? 2 : 1;
  int GB = (wid < 5) ? wid * 2 : wid + 5;

  f32x4 acc[8][4];
  const f32x4 zf = {0.0f, 0.0f, 0.0f, 0.0f};
#pragma unroll
  for (int mi = 0; mi < 8; ++mi)
#pragma unroll
    for (int j = 0; j < 4; ++j) acc[mi][j] = zf;

#pragma unroll 2
  for (int kt = 0; kt < 13; ++kt) {
    bf16x8 bfr[4];
    bfr[0] = *(const bf16x8*)(Bg + kt * 32768 + (2 * GB) * 1024 + lane * 16);
    bfr[1] = *(const bf16x8*)(Bg + kt * 32768 + (2 * GB + 1) * 1024 + lane * 16);
    if (NG == 2) {
      bfr[2] = *(const bf16x8*)(Bg + kt * 32768 + (2 * GB + 2) * 1024 + lane * 16);
      bfr[3] = *(const bf16x8*)(Bg + kt * 32768 + (2 * GB + 3) * 1024 + lane * 16);
    }
#pragma unroll
    for (int mi = 0; mi < 8; ++mi) {
      bf16x8 af = *(const bf16x8*)(sm + kt * 8192 + (lane >> 4) * 2048 +
                                   (mi * 16 + (lane & 15)) * 16);
      acc[mi][0] = __builtin_amdgcn_mfma_f32_16x16x32_bf16(af, bfr[0], acc[mi][0], 0, 0, 0);
      acc[mi][1] = __builtin_amdgcn_mfma_f32_16x16x32_bf16(af, bfr[1], acc[mi][1], 0, 0, 0);
      if (NG == 2) {
        acc[mi][2] = __builtin_amdgcn_mfma_f32_16x16x32_bf16(af, bfr[2], acc[mi][2], 0, 0, 0);
        acc[mi][3] = __builtin_amdgcn_mfma_f32_16x16x32_bf16(af, bfr[3], acc[mi][3], 0, 0, 0);
      }
    }
  }
  __syncthreads();  // all A reads done before P overwrites the region

  // ---- P = re^2+im^2 (bf16) @ LDS 0, stride 268; zero bins 208..255 ----
  u16* P = (u16*)sm;  // [128 frame][268]
#pragma unroll
  for (int j = 0; j < 2; ++j) {
    if (j < NG) {
      int bin = (GB + j) * 16 + (lane & 15);
#pragma unroll
      for (int mi = 0; mi < 8; ++mi)
#pragma unroll
        for (int r = 0; r < 4; ++r) {
          int row = mi * 16 + (lane >> 4) * 4 + r;
          float re = acc[mi][2 * j][r], im = acc[mi][2 * j + 1][r];
          P[row * P_STRIDE + bin] = f2bf(re * re + im * im);
        }
    }
  }
  {
    u32* P32 = (u32*)sm;  // zero bins 208..255 (u32 idx 104..127 per row)
    for (int i = tid; i < 3072; i += 512) {
      int row = i / 24, c = i - row * 24;
      P32[row * 134 + 104 + c] = 0;
    }
  }
  __syncthreads();

  // ---- GEMM2 (swapped): D[m][frame] = FB[m][bins] x P^T[bins][frame] ----
  f32x4 macc[4];
#pragma unroll
  for (int nf = 0; nf < 4; ++nf) macc[nf] = zf;
#pragma unroll
  for (int kt = 0; kt < 8; ++kt) {
    int krow = kt * 32 + (lane >> 4) * 8;
    bf16x8 pb = *(const bf16x8*)&P[(wid * 16 + (lane & 15)) * P_STRIDE + krow];
#pragma unroll
    for (int nf = 0; nf < 4; ++nf) {
      bf16x8 fa = *(const bf16x8*)&FBg[(nf * 16 + (lane & 15)) * 264 + krow];
      macc[nf] = __builtin_amdgcn_mfma_f32_16x16x32_bf16(fa, pb, macc[nf], 0, 0, 0);
    }
  }

  // ---- mel direct store (bf16): D col = frame, row = m ----
  int t = bx * 128 + wid * 16 + (lane & 15);
  if (t <= 1000) {
#pragma unroll
    for (int nf = 0; nf < 4; ++nf)
#pragma unroll
      for (int r = 0; r < 4; ++r) {
        int m = nf * 16 + (lane >> 4) * 4 + r;
        mel[((size_t)b * 64 + m) * MEL_STRIDE + t] = f2bf(macc[nf][r]);
      }
  }

  // ---- GEMM3 (fused MFCC): db = 10log10(max(mel,1e-10)) -> f16 LDS,
  //      D2[k][t] = DCT16[k][m] x db[t][m]. Wave reads only rows it wrote.
  _Float16* db = (_Float16*)(sm + 69632);  // [128 t][72] f16 (2-way conflicts)
  {
    int tl = wid * 16 + (lane & 15);  // local t row 0..127
#pragma unroll
    for (int nf = 0; nf < 4; ++nf)
#pragma unroll
      for (int r = 0; r < 4; ++r) {
        int m = nf * 16 + (lane >> 4) * 4 + r;
        float d = 10.0f * log10f(fmaxf(macc[nf][r], 1e-10f));
        db[tl * 72 + m] = (_Float16)d;
      }
    f32x4 mf0 = zf, mf1 = zf;
#pragma unroll
    for (int mkt = 0; mkt < 2; ++mkt) {
      int ms = mkt * 32 + (lane >> 4) * 8;
      f16x8 pb3 = *(const f16x8*)&db[(wid * 16 + (lane & 15)) * 72 + ms];
      f16x8 fa0 = *(const f16x8*)&DCTg[((lane & 15)) * 64 + ms];
      f16x8 fa1 = *(const f16x8*)&DCTg[(16 + (lane & 15)) * 64 + ms];
      mf0 = __builtin_amdgcn_mfma_f32_16x16x32_f16(fa0, pb3, mf0, 0, 0, 0);
      mf1 = __builtin_amdgcn_mfma_f32_16x16x32_f16(fa1, pb3, mf1, 0, 0, 0);
    }
    if (t <= 1000) {
#pragma unroll
      for (int r = 0; r < 4; ++r) {
        int k0 = (lane >> 4) * 4 + r;        // 0..15
        mfcc[((size_t)b * 20 + k0) * 1001 + t] = mf0[r];
        int k1 = 16 + (lane >> 4) * 4 + r;   // 16..31, keep <20
        if (k1 < 20)
          mfcc[((size_t)b * 20 + k1) * 1001 + t] = mf1[r];
      }
    }
  }
}

// Wave-parallel EMA scan: one wave per (b,m) row, 16 t/lane (bf16 input),
// affine map compose via shuffle scan.
__global__ __launch_bounds__(256) void k_ema(const u16* __restrict__ mel,
                                             float* __restrict__ outp) {
  int wid = threadIdx.x >> 6, lane = threadIdx.x & 63;
  int row = blockIdx.x * 4 + wid;  // 0..4095
  const u16* src = mel + (size_t)row * MEL_STRIDE + lane * 16;

  float x[16];
  if (lane < 63) {
    uint4 v0 = *(const uint4*)&src[0];  // 8 bf16
    uint4 v1 = *(const uint4*)&src[8];  // 8 bf16
    x[0] = bf2f(v0.x & 0xFFFF);  x[1] = bf2f(v0.x >> 16);
    x[2] = bf2f(v0.y & 0xFFFF);  x[3] = bf2f(v0.y >> 16);
    x[4] = bf2f(v0.z & 0xFFFF);  x[5] = bf2f(v0.z >> 16);
    x[6] = bf2f(v0.w & 0xFFFF);  x[7] = bf2f(v0.w >> 16);
    x[8] = bf2f(v1.x & 0xFFFF);  x[9] = bf2f(v1.x >> 16);
    x[10] = bf2f(v1.y & 0xFFFF); x[11] = bf2f(v1.y >> 16);
    x[12] = bf2f(v1.z & 0xFFFF); x[13] = bf2f(v1.z >> 16);
    x[14] = bf2f(v1.w & 0xFFFF); x[15] = bf2f(v1.w >> 16);
#pragma unroll
    for (int i = 0; i < 16; ++i)
      if (lane * 16 + i > 1000) x[i] = 0.0f;
  } else {
#pragma unroll
    for (int i = 0; i < 16; ++i) x[i] = 0.0f;
  }

  float B = 0.0f;
#pragma unroll
  for (int i = 0; i < 16; ++i) B = fmaf(0.98f, B, 0.02f * x[i]);
  float A = 1.0f;
#pragma unroll
  for (int i = 0; i < 16; ++i) A *= 0.98f;

#pragma unroll
  for (int d = 1; d < 64; d <<= 1) {
    float Ap = __shfl_up(A, d, 64);
    float Bp = __shfl_up(B, d, 64);
    if (lane >= d) {
      B = fmaf(A, Bp, B);
      A = A * Ap;
    }
  }
  float s = __shfl_up(B, 1, 64);
  if (lane == 0) s = 0.0f;

  float* dst = outp + (size_t)row * 1001 + lane * 16;
#pragma unroll
  for (int i = 0; i < 16; ++i) {
    s = fmaf(0.98f, s, 0.02f * x[i]);
    if (lane * 16 + i <= 1000) dst[i] = log1pf(x[i] / (s + 1e-6f));
  }
}

extern "C" void kernel_launch(void* const* d_in, const int* in_sizes, int n_in,
                              void* d_out, int out_size, void* d_ws, size_t ws_size,
                              hipStream_t stream) {
  const float* wav = (const float*)d_in[0];
  float* out = (float*)d_out;
  float* ws = (float*)d_ws;
  u16* mel = (u16*)(ws + OFF_MEL);

  hipFuncSetAttribute(reinterpret_cast<const void*>(k_gemm),
                      hipFuncAttributeMaxDynamicSharedMemorySize, 106496);

  hipLaunchKernelGGL(k_init, dim3(256), dim3(256), 0, stream, ws);
  hipLaunchKernelGGL(k_gemm, dim3(8, 64), dim3(512), 106496, stream, wav, ws, mel,
                     out + 4100096);
  hipLaunchKernelGGL(k_ema, dim3(1024), dim3(256), 0, stream, mel, out);
}

// Round 25
// 83.667 us; speedup vs baseline: 1.1297x; 1.0245x over previous
//
#include <hip/hip_runtime.h>

#define T_FRAMES 1001
#define MEL_STRIDE 1008
#define P_STRIDE 268

// ws float offsets
#define OFF_WIN 0          // [416] f32
#define OFF_BG  1696       // u16[13 ktile][16384] twiddles, chunked (106496 f)
#define OFF_FBC 108192     // u16 chunked FB: [8 kt][4 nf] chunks x 512 u16 (8192 f)
#define OFF_DCTC 120000    // f16 chunked DCT: [2 mkt][2 q] chunks x 512 f16 (1024 f)
#define OFF_MEL 13748128   // u16(bf16) [4096][1008]

typedef unsigned int u32;
typedef unsigned short u16;
typedef __attribute__((ext_vector_type(8))) short bf16x8;
typedef __attribute__((ext_vector_type(8))) _Float16 f16x8;
typedef __attribute__((ext_vector_type(4))) float f32x4;

__device__ __forceinline__ u16 f2bf(float f) {
  u32 u = __float_as_uint(f);
  u32 r = (u + 0x7FFFu + ((u >> 16) & 1u)) >> 16;
  return (u16)r;
}

__device__ __forceinline__ float bf2f(u32 h) {  // low 16 bits = bf16
  return __uint_as_float(h << 16);
}

__device__ __forceinline__ int reflect_idx(int g) {
  g = (g < 0) ? -g : g;
  g = (g >= 160000) ? (319998 - g) : g;
  return g;
}

__device__ __forceinline__ float melfb(int m, int f) {
  if (f > 200) return 0.0f;
  float freq = 40.0f * (float)f;
  float m_max = 2595.0f * log10f(1.0f + 8000.0f / 700.0f);
  float ms = m_max / 65.0f;
  float fp0 = 700.0f * (powf(10.0f, (float)(m)     * ms / 2595.0f) - 1.0f);
  float fp1 = 700.0f * (powf(10.0f, (float)(m + 1) * ms / 2595.0f) - 1.0f);
  float fp2 = 700.0f * (powf(10.0f, (float)(m + 2) * ms / 2595.0f) - 1.0f);
  float dn = (freq - fp0) / (fp1 - fp0);
  float up = (fp2 - freq) / (fp2 - fp1);
  return fmaxf(0.0f, fminf(dn, up));
}

__global__ __launch_bounds__(256) void k_init(float* __restrict__ ws) {
  float* win = ws + OFF_WIN;
  u16* bg = (u16*)(ws + OFF_BG);
  u16* fbc = (u16*)(ws + OFF_FBC);
  _Float16* dctc = (_Float16*)(ws + OFF_DCTC);
  const float W = 6.28318530717958647692f / 400.0f;
  int tid = blockIdx.x * 256 + threadIdx.x;
  int stride = gridDim.x * 256;
  for (int i = tid; i < 416; i += stride)
    win[i] = (i < 400) ? (0.5f - 0.5f * cosf((float)i * W)) : 0.0f;
  // FB chunked: chunk = kt*4+nf; lane l holds FB[nf*16+(l&15)][kt*32+(l>>4)*8+e]
  for (int i = tid; i < 8 * 4 * 512; i += stride) {
    int chunk = i >> 9, l = (i >> 3) & 63, e = i & 7;
    int kt = chunk >> 2, nf = chunk & 3;
    int m = nf * 16 + (l & 15);
    int f = kt * 32 + (l >> 4) * 8 + e;
    fbc[i] = f2bf(melfb(m, f));
  }
  // DCT chunked: chunk = mkt*2+q; lane l holds DCT[q*16+(l&15)][mkt*32+(l>>4)*8+e]
  for (int i = tid; i < 2 * 2 * 512; i += stride) {
    int chunk = i >> 9, l = (i >> 3) & 63, e = i & 7;
    int mkt = chunk >> 1, q = chunk & 1;
    int k = q * 16 + (l & 15);
    int m = mkt * 32 + (l >> 4) * 8 + e;
    float v = 0.0f;
    if (k < 20) {
      v = cosf(3.14159265358979323846f / 64.0f * ((float)m + 0.5f) * (float)k) * sqrtf(2.0f / 64.0f);
      if (k == 0) v *= 0.70710678118654752440f;
    }
    dctc[i] = (_Float16)v;
  }
  // twiddles, chunked: u16 index = kt*16384 + g*512 + khalf*128 + c15*8 + e
  for (int i = tid; i < 13 * 16384; i += stride) {
    int kt = i >> 14;
    int r = i & 16383;
    int g = r >> 9;
    int khalf = (r >> 7) & 3;
    int c15 = (r >> 3) & 15;
    int e = r & 7;
    int col = g * 16 + c15;
    int n = kt * 32 + khalf * 8 + e;
    int bin = ((col >> 5) << 4) | (col & 15);
    int type = (col >> 4) & 1;
    float v = 0.0f;
    if (n < 400 && bin <= 200) {
      float a = (float)((n * bin) % 400) * W;
      v = type ? -sinf(a) : cosf(a);
    }
    bg[i] = f2bf(v);
  }
}

// One block = 128 frames of one batch row; 512 threads = 8 waves.
// GEMM1: 1M x 8N, dead-column-trimmed (13 structural variants all land 60-67us
// — structurally converged at ~413 TF effective on this K=416 skinny GEMM).
// GEMM2: mel (bf16 store), FB fragments now chunk-linear (coalesced 1KB).
// GEMM3: fused MFCC via f16 MFMA, DCT fragments chunk-linear.
__global__ __launch_bounds__(512, 2) void k_gemm(const float* __restrict__ wav,
                                                 const float* __restrict__ ws,
                                                 u16* __restrict__ mel,
                                                 float* __restrict__ mfcc) {
  extern __shared__ char sm[];  // A: [13 kt][8192 B]; P overlays; db @69632
  const char* Bg = (const char*)(ws + OFF_BG);
  const char* FBc = (const char*)(ws + OFF_FBC);
  const char* DCTc = (const char*)(ws + OFF_DCTC);
  const float* win = ws + OFF_WIN;
  int tid = threadIdx.x, wid = tid >> 6, lane = tid & 63;
  int bx = blockIdx.x, b = blockIdx.y;
  const float* wv = wav + (size_t)b * 160000;

  // ---- A build, all 13 ktiles: 4 lanes per frame row (coalesced reads) ----
  {
    int kq = tid & 3, rowq = tid >> 2;
    int frame = bx * 128 + rowq;
    bool fvalid = (frame <= 1000);
#pragma unroll 4
    for (int kt = 0; kt < 13; ++kt) {
      int n0 = kt * 32 + kq * 8;
      int g0 = frame * 160 + n0 - 200;
      float ax[8];
      if (fvalid) {
        if (g0 >= 0 && g0 + 7 < 160000) {
          float4 u = *(const float4*)&wv[g0];
          float4 v = *(const float4*)&wv[g0 + 4];
          ax[0] = u.x; ax[1] = u.y; ax[2] = u.z; ax[3] = u.w;
          ax[4] = v.x; ax[5] = v.y; ax[6] = v.z; ax[7] = v.w;
        } else {
#pragma unroll
          for (int e = 0; e < 8; ++e) ax[e] = wv[reflect_idx(g0 + e)];
        }
      } else {
#pragma unroll
        for (int e = 0; e < 8; ++e) ax[e] = 0.0f;
      }
      float4 w0 = *(const float4*)&win[n0];
      float4 w1 = *(const float4*)&win[n0 + 4];
      uint4 pk;
      pk.x = (u32)f2bf(ax[0] * w0.x) | ((u32)f2bf(ax[1] * w0.y) << 16);
      pk.y = (u32)f2bf(ax[2] * w0.z) | ((u32)f2bf(ax[3] * w0.w) << 16);
      pk.z = (u32)f2bf(ax[4] * w1.x) | ((u32)f2bf(ax[5] * w1.y) << 16);
      pk.w = (u32)f2bf(ax[6] * w1.z) | ((u32)f2bf(ax[7] * w1.w) << 16);
      *(uint4*)(sm + kt * 8192 + kq * 2048 + rowq * 16) = pk;
    }
  }
  __syncthreads();

  // ---- GEMM1: K-loop at unroll-2, 1M x 8N (13 bingroups, bins 0..207) ----
  int NG = (wid < 5) ? 2 : 1;
  int GB = (wid < 5) ? wid * 2 : wid + 5;

  f32x4 acc[8][4];
  const f32x4 zf = {0.0f, 0.0f, 0.0f, 0.0f};
#pragma unroll
  for (int mi = 0; mi < 8; ++mi)
#pragma unroll
    for (int j = 0; j < 4; ++j) acc[mi][j] = zf;

#pragma unroll 2
  for (int kt = 0; kt < 13; ++kt) {
    bf16x8 bfr[4];
    bfr[0] = *(const bf16x8*)(Bg + kt * 32768 + (2 * GB) * 1024 + lane * 16);
    bfr[1] = *(const bf16x8*)(Bg + kt * 32768 + (2 * GB + 1) * 1024 + lane * 16);
    if (NG == 2) {
      bfr[2] = *(const bf16x8*)(Bg + kt * 32768 + (2 * GB + 2) * 1024 + lane * 16);
      bfr[3] = *(const bf16x8*)(Bg + kt * 32768 + (2 * GB + 3) * 1024 + lane * 16);
    }
#pragma unroll
    for (int mi = 0; mi < 8; ++mi) {
      bf16x8 af = *(const bf16x8*)(sm + kt * 8192 + (lane >> 4) * 2048 +
                                   (mi * 16 + (lane & 15)) * 16);
      acc[mi][0] = __builtin_amdgcn_mfma_f32_16x16x32_bf16(af, bfr[0], acc[mi][0], 0, 0, 0);
      acc[mi][1] = __builtin_amdgcn_mfma_f32_16x16x32_bf16(af, bfr[1], acc[mi][1], 0, 0, 0);
      if (NG == 2) {
        acc[mi][2] = __builtin_amdgcn_mfma_f32_16x16x32_bf16(af, bfr[2], acc[mi][2], 0, 0, 0);
        acc[mi][3] = __builtin_amdgcn_mfma_f32_16x16x32_bf16(af, bfr[3], acc[mi][3], 0, 0, 0);
      }
    }
  }
  __syncthreads();  // all A reads done before P overwrites the region

  // ---- P = re^2+im^2 (bf16) @ LDS 0, stride 268; zero bins 208..255 ----
  u16* P = (u16*)sm;  // [128 frame][268]
#pragma unroll
  for (int j = 0; j < 2; ++j) {
    if (j < NG) {
      int bin = (GB + j) * 16 + (lane & 15);
#pragma unroll
      for (int mi = 0; mi < 8; ++mi)
#pragma unroll
        for (int r = 0; r < 4; ++r) {
          int row = mi * 16 + (lane >> 4) * 4 + r;
          float re = acc[mi][2 * j][r], im = acc[mi][2 * j + 1][r];
          P[row * P_STRIDE + bin] = f2bf(re * re + im * im);
        }
    }
  }
  {
    u32* P32 = (u32*)sm;  // zero bins 208..255 (u32 idx 104..127 per row)
    for (int i = tid; i < 3072; i += 512) {
      int row = i / 24, c = i - row * 24;
      P32[row * 134 + 104 + c] = 0;
    }
  }
  __syncthreads();

  // ---- GEMM2 (swapped): D[m][frame] = FB[m][bins] x P^T[bins][frame] ----
  f32x4 macc[4];
#pragma unroll
  for (int nf = 0; nf < 4; ++nf) macc[nf] = zf;
#pragma unroll
  for (int kt = 0; kt < 8; ++kt) {
    int krow = kt * 32 + (lane >> 4) * 8;
    bf16x8 pb = *(const bf16x8*)&P[(wid * 16 + (lane & 15)) * P_STRIDE + krow];
#pragma unroll
    for (int nf = 0; nf < 4; ++nf) {
      bf16x8 fa = *(const bf16x8*)(FBc + (kt * 4 + nf) * 1024 + lane * 16);
      macc[nf] = __builtin_amdgcn_mfma_f32_16x16x32_bf16(fa, pb, macc[nf], 0, 0, 0);
    }
  }

  // ---- mel direct store (bf16): D col = frame, row = m ----
  int t = bx * 128 + wid * 16 + (lane & 15);
  if (t <= 1000) {
#pragma unroll
    for (int nf = 0; nf < 4; ++nf)
#pragma unroll
      for (int r = 0; r < 4; ++r) {
        int m = nf * 16 + (lane >> 4) * 4 + r;
        mel[((size_t)b * 64 + m) * MEL_STRIDE + t] = f2bf(macc[nf][r]);
      }
  }

  // ---- GEMM3 (fused MFCC): db = 10log10(max(mel,1e-10)) -> f16 LDS,
  //      D2[k][t] = DCT16[k][m] x db[t][m]. Wave reads only rows it wrote.
  _Float16* db = (_Float16*)(sm + 69632);  // [128 t][72] f16 (2-way conflicts)
  {
    int tl = wid * 16 + (lane & 15);  // local t row 0..127
#pragma unroll
    for (int nf = 0; nf < 4; ++nf)
#pragma unroll
      for (int r = 0; r < 4; ++r) {
        int m = nf * 16 + (lane >> 4) * 4 + r;
        float d = 10.0f * log10f(fmaxf(macc[nf][r], 1e-10f));
        db[tl * 72 + m] = (_Float16)d;
      }
    f32x4 mf0 = zf, mf1 = zf;
#pragma unroll
    for (int mkt = 0; mkt < 2; ++mkt) {
      int ms = mkt * 32 + (lane >> 4) * 8;
      f16x8 pb3 = *(const f16x8*)&db[(wid * 16 + (lane & 15)) * 72 + ms];
      f16x8 fa0 = *(const f16x8*)(DCTc + (mkt * 2 + 0) * 1024 + lane * 16);
      f16x8 fa1 = *(const f16x8*)(DCTc + (mkt * 2 + 1) * 1024 + lane * 16);
      mf0 = __builtin_amdgcn_mfma_f32_16x16x32_f16(fa0, pb3, mf0, 0, 0, 0);
      mf1 = __builtin_amdgcn_mfma_f32_16x16x32_f16(fa1, pb3, mf1, 0, 0, 0);
    }
    if (t <= 1000) {
#pragma unroll
      for (int r = 0; r < 4; ++r) {
        int k0 = (lane >> 4) * 4 + r;        // 0..15
        mfcc[((size_t)b * 20 + k0) * 1001 + t] = mf0[r];
        int k1 = 16 + (lane >> 4) * 4 + r;   // 16..31, keep <20
        if (k1 < 20)
          mfcc[((size_t)b * 20 + k1) * 1001 + t] = mf1[r];
      }
    }
  }
}

// Wave-parallel EMA scan: one wave per (b,m) row, 16 t/lane (bf16 input),
// affine map compose via shuffle scan.
__global__ __launch_bounds__(256) void k_ema(const u16* __restrict__ mel,
                                             float* __restrict__ outp) {
  int wid = threadIdx.x >> 6, lane = threadIdx.x & 63;
  int row = blockIdx.x * 4 + wid;  // 0..4095
  const u16* src = mel + (size_t)row * MEL_STRIDE + lane * 16;

  float x[16];
  if (lane < 63) {
    uint4 v0 = *(const uint4*)&src[0];  // 8 bf16
    uint4 v1 = *(const uint4*)&src[8];  // 8 bf16
    x[0] = bf2f(v0.x & 0xFFFF);  x[1] = bf2f(v0.x >> 16);
    x[2] = bf2f(v0.y & 0xFFFF);  x[3] = bf2f(v0.y >> 16);
    x[4] = bf2f(v0.z & 0xFFFF);  x[5] = bf2f(v0.z >> 16);
    x[6] = bf2f(v0.w & 0xFFFF);  x[7] = bf2f(v0.w >> 16);
    x[8] = bf2f(v1.x & 0xFFFF);  x[9] = bf2f(v1.x >> 16);
    x[10] = bf2f(v1.y & 0xFFFF); x[11] = bf2f(v1.y >> 16);
    x[12] = bf2f(v1.z & 0xFFFF); x[13] = bf2f(v1.z >> 16);
    x[14] = bf2f(v1.w & 0xFFFF); x[15] = bf2f(v1.w >> 16);
#pragma unroll
    for (int i = 0; i < 16; ++i)
      if (lane * 16 + i > 1000) x[i] = 0.0f;
  } else {
#pragma unroll
    for (int i = 0; i < 16; ++i) x[i] = 0.0f;
  }

  float B = 0.0f;
#pragma unroll
  for (int i = 0; i < 16; ++i) B = fmaf(0.98f, B, 0.02f * x[i]);
  float A = 1.0f;
#pragma unroll
  for (int i = 0; i < 16; ++i) A *= 0.98f;

#pragma unroll
  for (int d = 1; d < 64; d <<= 1) {
    float Ap = __shfl_up(A, d, 64);
    float Bp = __shfl_up(B, d, 64);
    if (lane >= d) {
      B = fmaf(A, Bp, B);
      A = A * Ap;
    }
  }
  float s = __shfl_up(B, 1, 64);
  if (lane == 0) s = 0.0f;

  float* dst = outp + (size_t)row * 1001 + lane * 16;
#pragma unroll
  for (int i = 0; i < 16; ++i) {
    s = fmaf(0.98f, s, 0.02f * x[i]);
    if (lane * 16 + i <= 1000) dst[i] = log1pf(x[i] / (s + 1e-6f));
  }
}

extern "C" void kernel_launch(void* const* d_in, const int* in_sizes, int n_in,
                              void* d_out, int out_size, void* d_ws, size_t ws_size,
                              hipStream_t stream) {
  const float* wav = (const float*)d_in[0];
  float* out = (float*)d_out;
  float* ws = (float*)d_ws;
  u16* mel = (u16*)(ws + OFF_MEL);

  hipFuncSetAttribute(reinterpret_cast<const void*>(k_gemm),
                      hipFuncAttributeMaxDynamicSharedMemorySize, 106496);

  hipLaunchKernelGGL(k_init, dim3(256), dim3(256), 0, stream, ws);
  hipLaunchKernelGGL(k_gemm, dim3(8, 64), dim3(512), 106496, stream, wav, ws, mel,
                     out + 4100096);
  hipLaunchKernelGGL(k_ema, dim3(1024), dim3(256), 0, stream, mel, out);
}

// Round 26
// 79.405 us; speedup vs baseline: 1.1904x; 1.0537x over previous
//
#include <hip/hip_runtime.h>

#define T_FRAMES 1001
#define MEL_STRIDE 1008
#define P_STRIDE 268

// ws float offsets
#define OFF_WIN 0          // [416] f32
#define OFF_BG  1696       // u16[13 ktile][16384] twiddles, chunked (106496 f)
#define OFF_FBC 108192     // u16 chunked FB: [8 kt][4 nf] chunks x 512 u16 (8192 f)
#define OFF_DCTC 120000    // f16 chunked DCT: [2 mkt][2 q] chunks x 512 f16 (1024 f)
#define OFF_MEL 13748128   // u16(bf16) [4096][1008]

typedef unsigned int u32;
typedef unsigned short u16;
typedef __attribute__((ext_vector_type(8))) short bf16x8;
typedef __attribute__((ext_vector_type(8))) _Float16 f16x8;
typedef __attribute__((ext_vector_type(4))) float f32x4;

__device__ __forceinline__ u16 f2bf(float f) {
  u32 u = __float_as_uint(f);
  u32 r = (u + 0x7FFFu + ((u >> 16) & 1u)) >> 16;
  return (u16)r;
}

__device__ __forceinline__ float bf2f(u32 h) {  // low 16 bits = bf16
  return __uint_as_float(h << 16);
}

__device__ __forceinline__ int reflect_idx(int g) {
  g = (g < 0) ? -g : g;
  g = (g >= 160000) ? (319998 - g) : g;
  return g;
}

__device__ __forceinline__ float melfb(int m, int f) {
  if (f > 200) return 0.0f;
  float freq = 40.0f * (float)f;
  float m_max = 2595.0f * log10f(1.0f + 8000.0f / 700.0f);
  float ms = m_max / 65.0f;
  float fp0 = 700.0f * (powf(10.0f, (float)(m)     * ms / 2595.0f) - 1.0f);
  float fp1 = 700.0f * (powf(10.0f, (float)(m + 1) * ms / 2595.0f) - 1.0f);
  float fp2 = 700.0f * (powf(10.0f, (float)(m + 2) * ms / 2595.0f) - 1.0f);
  float dn = (freq - fp0) / (fp1 - fp0);
  float up = (fp2 - freq) / (fp2 - fp1);
  return fmaxf(0.0f, fminf(dn, up));
}

__global__ __launch_bounds__(256) void k_init(float* __restrict__ ws) {
  float* win = ws + OFF_WIN;
  u16* bg = (u16*)(ws + OFF_BG);
  u16* fbc = (u16*)(ws + OFF_FBC);
  _Float16* dctc = (_Float16*)(ws + OFF_DCTC);
  const float W = 6.28318530717958647692f / 400.0f;
  int tid = blockIdx.x * 256 + threadIdx.x;
  int stride = gridDim.x * 256;
  for (int i = tid; i < 416; i += stride)
    win[i] = (i < 400) ? (0.5f - 0.5f * cosf((float)i * W)) : 0.0f;
  // FB chunked: chunk = kt*4+nf; lane l holds FB[nf*16+(l&15)][kt*32+(l>>4)*8+e]
  for (int i = tid; i < 8 * 4 * 512; i += stride) {
    int chunk = i >> 9, l = (i >> 3) & 63, e = i & 7;
    int kt = chunk >> 2, nf = chunk & 3;
    int m = nf * 16 + (l & 15);
    int f = kt * 32 + (l >> 4) * 8 + e;
    fbc[i] = f2bf(melfb(m, f));
  }
  // DCT chunked: chunk = mkt*2+q; lane l holds DCT[q*16+(l&15)][mkt*32+(l>>4)*8+e]
  for (int i = tid; i < 2 * 2 * 512; i += stride) {
    int chunk = i >> 9, l = (i >> 3) & 63, e = i & 7;
    int mkt = chunk >> 1, q = chunk & 1;
    int k = q * 16 + (l & 15);
    int m = mkt * 32 + (l >> 4) * 8 + e;
    float v = 0.0f;
    if (k < 20) {
      v = cosf(3.14159265358979323846f / 64.0f * ((float)m + 0.5f) * (float)k) * sqrtf(2.0f / 64.0f);
      if (k == 0) v *= 0.70710678118654752440f;
    }
    dctc[i] = (_Float16)v;
  }
  // twiddles, chunked: u16 index = kt*16384 + g*512 + khalf*128 + c15*8 + e
  for (int i = tid; i < 13 * 16384; i += stride) {
    int kt = i >> 14;
    int r = i & 16383;
    int g = r >> 9;
    int khalf = (r >> 7) & 3;
    int c15 = (r >> 3) & 15;
    int e = r & 7;
    int col = g * 16 + c15;
    int n = kt * 32 + khalf * 8 + e;
    int bin = ((col >> 5) << 4) | (col & 15);
    int type = (col >> 4) & 1;
    float v = 0.0f;
    if (n < 400 && bin <= 200) {
      float a = (float)((n * bin) % 400) * W;
      v = type ? -sinf(a) : cosf(a);
    }
    bg[i] = f2bf(v);
  }
}

// One block = 128 frames of one batch row; 512 threads = 8 waves.
// Flat 512-block grid with bijective XCD-chunk swizzle (nwg%8==0): hw block n
// -> work (n&7)*64 + (n>>3), so the 8 bx-blocks sharing a wav row b (640 KB,
// read 2.6x by overlapping frames) and the 416 KB B-table co-locate on one
// XCD's L2 -> A-build/B loads pay ~200cyc L2 instead of L3/HBM latency.
// (At 2 waves/SIMD — forced by the 128-AGPR acc — latency is fully exposed,
// so this is a latency lever, matching the measured stall regime.)
// GEMM1: 1M x 8N, dead-column-trimmed. GEMM2: mel (bf16), FB chunk-linear.
// GEMM3: fused MFCC via f16 MFMA, DCT chunk-linear.
__global__ __launch_bounds__(512, 2) void k_gemm(const float* __restrict__ wav,
                                                 const float* __restrict__ ws,
                                                 u16* __restrict__ mel,
                                                 float* __restrict__ mfcc) {
  extern __shared__ char sm[];  // A: [13 kt][8192 B]; P overlays; db @69632
  const char* Bg = (const char*)(ws + OFF_BG);
  const char* FBc = (const char*)(ws + OFF_FBC);
  const char* DCTc = (const char*)(ws + OFF_DCTC);
  const float* win = ws + OFF_WIN;
  int tid = threadIdx.x, wid = tid >> 6, lane = tid & 63;
  // XCD-chunk swizzle: 512 blocks, 8 XCDs -> 64 consecutive work items per XCD
  int work = (blockIdx.x & 7) * 64 + (blockIdx.x >> 3);
  int b = work >> 3, bx = work & 7;
  const float* wv = wav + (size_t)b * 160000;

  // ---- A build, all 13 ktiles: 4 lanes per frame row (coalesced reads) ----
  {
    int kq = tid & 3, rowq = tid >> 2;
    int frame = bx * 128 + rowq;
    bool fvalid = (frame <= 1000);
#pragma unroll 4
    for (int kt = 0; kt < 13; ++kt) {
      int n0 = kt * 32 + kq * 8;
      int g0 = frame * 160 + n0 - 200;
      float ax[8];
      if (fvalid) {
        if (g0 >= 0 && g0 + 7 < 160000) {
          float4 u = *(const float4*)&wv[g0];
          float4 v = *(const float4*)&wv[g0 + 4];
          ax[0] = u.x; ax[1] = u.y; ax[2] = u.z; ax[3] = u.w;
          ax[4] = v.x; ax[5] = v.y; ax[6] = v.z; ax[7] = v.w;
        } else {
#pragma unroll
          for (int e = 0; e < 8; ++e) ax[e] = wv[reflect_idx(g0 + e)];
        }
      } else {
#pragma unroll
        for (int e = 0; e < 8; ++e) ax[e] = 0.0f;
      }
      float4 w0 = *(const float4*)&win[n0];
      float4 w1 = *(const float4*)&win[n0 + 4];
      uint4 pk;
      pk.x = (u32)f2bf(ax[0] * w0.x) | ((u32)f2bf(ax[1] * w0.y) << 16);
      pk.y = (u32)f2bf(ax[2] * w0.z) | ((u32)f2bf(ax[3] * w0.w) << 16);
      pk.z = (u32)f2bf(ax[4] * w1.x) | ((u32)f2bf(ax[5] * w1.y) << 16);
      pk.w = (u32)f2bf(ax[6] * w1.z) | ((u32)f2bf(ax[7] * w1.w) << 16);
      *(uint4*)(sm + kt * 8192 + kq * 2048 + rowq * 16) = pk;
    }
  }
  __syncthreads();

  // ---- GEMM1: K-loop at unroll-2, 1M x 8N (13 bingroups, bins 0..207) ----
  int NG = (wid < 5) ? 2 : 1;
  int GB = (wid < 5) ? wid * 2 : wid + 5;

  f32x4 acc[8][4];
  const f32x4 zf = {0.0f, 0.0f, 0.0f, 0.0f};
#pragma unroll
  for (int mi = 0; mi < 8; ++mi)
#pragma unroll
    for (int j = 0; j < 4; ++j) acc[mi][j] = zf;

#pragma unroll 2
  for (int kt = 0; kt < 13; ++kt) {
    bf16x8 bfr[4];
    bfr[0] = *(const bf16x8*)(Bg + kt * 32768 + (2 * GB) * 1024 + lane * 16);
    bfr[1] = *(const bf16x8*)(Bg + kt * 32768 + (2 * GB + 1) * 1024 + lane * 16);
    if (NG == 2) {
      bfr[2] = *(const bf16x8*)(Bg + kt * 32768 + (2 * GB + 2) * 1024 + lane * 16);
      bfr[3] = *(const bf16x8*)(Bg + kt * 32768 + (2 * GB + 3) * 1024 + lane * 16);
    }
#pragma unroll
    for (int mi = 0; mi < 8; ++mi) {
      bf16x8 af = *(const bf16x8*)(sm + kt * 8192 + (lane >> 4) * 2048 +
                                   (mi * 16 + (lane & 15)) * 16);
      acc[mi][0] = __builtin_amdgcn_mfma_f32_16x16x32_bf16(af, bfr[0], acc[mi][0], 0, 0, 0);
      acc[mi][1] = __builtin_amdgcn_mfma_f32_16x16x32_bf16(af, bfr[1], acc[mi][1], 0, 0, 0);
      if (NG == 2) {
        acc[mi][2] = __builtin_amdgcn_mfma_f32_16x16x32_bf16(af, bfr[2], acc[mi][2], 0, 0, 0);
        acc[mi][3] = __builtin_amdgcn_mfma_f32_16x16x32_bf16(af, bfr[3], acc[mi][3], 0, 0, 0);
      }
    }
  }
  __syncthreads();  // all A reads done before P overwrites the region

  // ---- P = re^2+im^2 (bf16) @ LDS 0, stride 268; zero bins 208..255 ----
  u16* P = (u16*)sm;  // [128 frame][268]
#pragma unroll
  for (int j = 0; j < 2; ++j) {
    if (j < NG) {
      int bin = (GB + j) * 16 + (lane & 15);
#pragma unroll
      for (int mi = 0; mi < 8; ++mi)
#pragma unroll
        for (int r = 0; r < 4; ++r) {
          int row = mi * 16 + (lane >> 4) * 4 + r;
          float re = acc[mi][2 * j][r], im = acc[mi][2 * j + 1][r];
          P[row * P_STRIDE + bin] = f2bf(re * re + im * im);
        }
    }
  }
  {
    u32* P32 = (u32*)sm;  // zero bins 208..255 (u32 idx 104..127 per row)
    for (int i = tid; i < 3072; i += 512) {
      int row = i / 24, c = i - row * 24;
      P32[row * 134 + 104 + c] = 0;
    }
  }
  __syncthreads();

  // ---- GEMM2 (swapped): D[m][frame] = FB[m][bins] x P^T[bins][frame] ----
  f32x4 macc[4];
#pragma unroll
  for (int nf = 0; nf < 4; ++nf) macc[nf] = zf;
#pragma unroll
  for (int kt = 0; kt < 8; ++kt) {
    int krow = kt * 32 + (lane >> 4) * 8;
    bf16x8 pb = *(const bf16x8*)&P[(wid * 16 + (lane & 15)) * P_STRIDE + krow];
#pragma unroll
    for (int nf = 0; nf < 4; ++nf) {
      bf16x8 fa = *(const bf16x8*)(FBc + (kt * 4 + nf) * 1024 + lane * 16);
      macc[nf] = __builtin_amdgcn_mfma_f32_16x16x32_bf16(fa, pb, macc[nf], 0, 0, 0);
    }
  }

  // ---- mel direct store (bf16): D col = frame, row = m ----
  int t = bx * 128 + wid * 16 + (lane & 15);
  if (t <= 1000) {
#pragma unroll
    for (int nf = 0; nf < 4; ++nf)
#pragma unroll
      for (int r = 0; r < 4; ++r) {
        int m = nf * 16 + (lane >> 4) * 4 + r;
        mel[((size_t)b * 64 + m) * MEL_STRIDE + t] = f2bf(macc[nf][r]);
      }
  }

  // ---- GEMM3 (fused MFCC): db = 10log10(max(mel,1e-10)) -> f16 LDS,
  //      D2[k][t] = DCT16[k][m] x db[t][m]. Wave reads only rows it wrote.
  _Float16* db = (_Float16*)(sm + 69632);  // [128 t][72] f16 (2-way conflicts)
  {
    int tl = wid * 16 + (lane & 15);  // local t row 0..127
#pragma unroll
    for (int nf = 0; nf < 4; ++nf)
#pragma unroll
      for (int r = 0; r < 4; ++r) {
        int m = nf * 16 + (lane >> 4) * 4 + r;
        float d = 10.0f * log10f(fmaxf(macc[nf][r], 1e-10f));
        db[tl * 72 + m] = (_Float16)d;
      }
    f32x4 mf0 = zf, mf1 = zf;
#pragma unroll
    for (int mkt = 0; mkt < 2; ++mkt) {
      int ms = mkt * 32 + (lane >> 4) * 8;
      f16x8 pb3 = *(const f16x8*)&db[(wid * 16 + (lane & 15)) * 72 + ms];
      f16x8 fa0 = *(const f16x8*)(DCTc + (mkt * 2 + 0) * 1024 + lane * 16);
      f16x8 fa1 = *(const f16x8*)(DCTc + (mkt * 2 + 1) * 1024 + lane * 16);
      mf0 = __builtin_amdgcn_mfma_f32_16x16x32_f16(fa0, pb3, mf0, 0, 0, 0);
      mf1 = __builtin_amdgcn_mfma_f32_16x16x32_f16(fa1, pb3, mf1, 0, 0, 0);
    }
    if (t <= 1000) {
#pragma unroll
      for (int r = 0; r < 4; ++r) {
        int k0 = (lane >> 4) * 4 + r;        // 0..15
        mfcc[((size_t)b * 20 + k0) * 1001 + t] = mf0[r];
        int k1 = 16 + (lane >> 4) * 4 + r;   // 16..31, keep <20
        if (k1 < 20)
          mfcc[((size_t)b * 20 + k1) * 1001 + t] = mf1[r];
      }
    }
  }
}

// Wave-parallel EMA scan: one wave per (b,m) row, 16 t/lane (bf16 input),
// affine map compose via shuffle scan.
__global__ __launch_bounds__(256) void k_ema(const u16* __restrict__ mel,
                                             float* __restrict__ outp) {
  int wid = threadIdx.x >> 6, lane = threadIdx.x & 63;
  int row = blockIdx.x * 4 + wid;  // 0..4095
  const u16* src = mel + (size_t)row * MEL_STRIDE + lane * 16;

  float x[16];
  if (lane < 63) {
    uint4 v0 = *(const uint4*)&src[0];  // 8 bf16
    uint4 v1 = *(const uint4*)&src[8];  // 8 bf16
    x[0] = bf2f(v0.x & 0xFFFF);  x[1] = bf2f(v0.x >> 16);
    x[2] = bf2f(v0.y & 0xFFFF);  x[3] = bf2f(v0.y >> 16);
    x[4] = bf2f(v0.z & 0xFFFF);  x[5] = bf2f(v0.z >> 16);
    x[6] = bf2f(v0.w & 0xFFFF);  x[7] = bf2f(v0.w >> 16);
    x[8] = bf2f(v1.x & 0xFFFF);  x[9] = bf2f(v1.x >> 16);
    x[10] = bf2f(v1.y & 0xFFFF); x[11] = bf2f(v1.y >> 16);
    x[12] = bf2f(v1.z & 0xFFFF); x[13] = bf2f(v1.z >> 16);
    x[14] = bf2f(v1.w & 0xFFFF); x[15] = bf2f(v1.w >> 16);
#pragma unroll
    for (int i = 0; i < 16; ++i)
      if (lane * 16 + i > 1000) x[i] = 0.0f;
  } else {
#pragma unroll
    for (int i = 0; i < 16; ++i) x[i] = 0.0f;
  }

  float B = 0.0f;
#pragma unroll
  for (int i = 0; i < 16; ++i) B = fmaf(0.98f, B, 0.02f * x[i]);
  float A = 1.0f;
#pragma unroll
  for (int i = 0; i < 16; ++i) A *= 0.98f;

#pragma unroll
  for (int d = 1; d < 64; d <<= 1) {
    float Ap = __shfl_up(A, d, 64);
    float Bp = __shfl_up(B, d, 64);
    if (lane >= d) {
      B = fmaf(A, Bp, B);
      A = A * Ap;
    }
  }
  float s = __shfl_up(B, 1, 64);
  if (lane == 0) s = 0.0f;

  float* dst = outp + (size_t)row * 1001 + lane * 16;
#pragma unroll
  for (int i = 0; i < 16; ++i) {
    s = fmaf(0.98f, s, 0.02f * x[i]);
    if (lane * 16 + i <= 1000) dst[i] = log1pf(x[i] / (s + 1e-6f));
  }
}

extern "C" void kernel_launch(void* const* d_in, const int* in_sizes, int n_in,
                              void* d_out, int out_size, void* d_ws, size_t ws_size,
                              hipStream_t stream) {
  const float* wav = (const float*)d_in[0];
  float* out = (float*)d_out;
  float* ws = (float*)d_ws;
  u16* mel = (u16*)(ws + OFF_MEL);

  hipFuncSetAttribute(reinterpret_cast<const void*>(k_gemm),
                      hipFuncAttributeMaxDynamicSharedMemorySize, 106496);

  hipLaunchKernelGGL(k_init, dim3(256), dim3(256), 0, stream, ws);
  hipLaunchKernelGGL(k_gemm, dim3(512), dim3(512), 106496, stream, wav, ws, mel,
                     out + 4100096);
  hipLaunchKernelGGL(k_ema, dim3(1024), dim3(256), 0, stream, mel, out);
}

// Round 27
// 73.749 us; speedup vs baseline: 1.2817x; 1.0767x over previous
//
#include <hip/hip_runtime.h>

#define T_FRAMES 1001
#define MEL_STRIDE 1008
#define P_STRIDE 268

// ws float offsets
#define OFF_WIN 0          // [416] f32
#define OFF_BG  1696       // u16[13 ktile][16384] twiddles, chunked (106496 f)
#define OFF_FBC 108192     // u16 chunked FB: [8 kt][4 nf] chunks x 512 u16 (8192 f)
#define OFF_DCTC 120000    // f16 chunked DCT: [2 mkt][2 q] chunks x 512 f16 (1024 f)
#define OFF_MEL 13748128   // u16(bf16) [4096][1008]

typedef unsigned int u32;
typedef unsigned short u16;
typedef __attribute__((ext_vector_type(8))) short bf16x8;
typedef __attribute__((ext_vector_type(8))) _Float16 f16x8;
typedef __attribute__((ext_vector_type(4))) float f32x4;

__device__ __forceinline__ u16 f2bf(float f) {
  u32 u = __float_as_uint(f);
  u32 r = (u + 0x7FFFu + ((u >> 16) & 1u)) >> 16;
  return (u16)r;
}

__device__ __forceinline__ float bf2f(u32 h) {  // low 16 bits = bf16
  return __uint_as_float(h << 16);
}

__device__ __forceinline__ int reflect_idx(int g) {
  g = (g < 0) ? -g : g;
  g = (g >= 160000) ? (319998 - g) : g;
  return g;
}

__device__ __forceinline__ float melfb(int m, int f) {
  if (f > 200) return 0.0f;
  float freq = 40.0f * (float)f;
  float m_max = 2595.0f * log10f(1.0f + 8000.0f / 700.0f);
  float ms = m_max / 65.0f;
  float fp0 = 700.0f * (powf(10.0f, (float)(m)     * ms / 2595.0f) - 1.0f);
  float fp1 = 700.0f * (powf(10.0f, (float)(m + 1) * ms / 2595.0f) - 1.0f);
  float fp2 = 700.0f * (powf(10.0f, (float)(m + 2) * ms / 2595.0f) - 1.0f);
  float dn = (freq - fp0) / (fp1 - fp0);
  float up = (fp2 - freq) / (fp2 - fp1);
  return fmaxf(0.0f, fminf(dn, up));
}

__global__ __launch_bounds__(256) void k_init(float* __restrict__ ws) {
  float* win = ws + OFF_WIN;
  u16* bg = (u16*)(ws + OFF_BG);
  u16* fbc = (u16*)(ws + OFF_FBC);
  _Float16* dctc = (_Float16*)(ws + OFF_DCTC);
  const float W = 6.28318530717958647692f / 400.0f;
  int tid = blockIdx.x * 256 + threadIdx.x;
  int stride = gridDim.x * 256;
  for (int i = tid; i < 416; i += stride)
    win[i] = (i < 400) ? (0.5f - 0.5f * cosf((float)i * W)) : 0.0f;
  // FB chunked: chunk = kt*4+nf; lane l holds FB[nf*16+(l&15)][kt*32+(l>>4)*8+e]
  for (int i = tid; i < 8 * 4 * 512; i += stride) {
    int chunk = i >> 9, l = (i >> 3) & 63, e = i & 7;
    int kt = chunk >> 2, nf = chunk & 3;
    int m = nf * 16 + (l & 15);
    int f = kt * 32 + (l >> 4) * 8 + e;
    fbc[i] = f2bf(melfb(m, f));
  }
  // DCT chunked: chunk = mkt*2+q; lane l holds DCT[q*16+(l&15)][mkt*32+(l>>4)*8+e]
  for (int i = tid; i < 2 * 2 * 512; i += stride) {
    int chunk = i >> 9, l = (i >> 3) & 63, e = i & 7;
    int mkt = chunk >> 1, q = chunk & 1;
    int k = q * 16 + (l & 15);
    int m = mkt * 32 + (l >> 4) * 8 + e;
    float v = 0.0f;
    if (k < 20) {
      v = cosf(3.14159265358979323846f / 64.0f * ((float)m + 0.5f) * (float)k) * sqrtf(2.0f / 64.0f);
      if (k == 0) v *= 0.70710678118654752440f;
    }
    dctc[i] = (_Float16)v;
  }
  // twiddles, chunked: u16 index = kt*16384 + g*512 + khalf*128 + c15*8 + e
  for (int i = tid; i < 13 * 16384; i += stride) {
    int kt = i >> 14;
    int r = i & 16383;
    int g = r >> 9;
    int khalf = (r >> 7) & 3;
    int c15 = (r >> 3) & 15;
    int e = r & 7;
    int col = g * 16 + c15;
    int n = kt * 32 + khalf * 8 + e;
    int bin = ((col >> 5) << 4) | (col & 15);
    int type = (col >> 4) & 1;
    float v = 0.0f;
    if (n < 400 && bin <= 200) {
      float a = (float)((n * bin) % 400) * W;
      v = type ? -sinf(a) : cosf(a);
    }
    bg[i] = f2bf(v);
  }
}

// One block = 128 frames of one batch row; 512 threads = 8 waves.
// Flat 512-block grid with bijective XCD-chunk swizzle (r26: -4.3us).
// GEMM1: 1M x 8N, dead-column-trimmed. GEMM2: mel (bf16), FB chunk-linear.
// GEMM3: fused MFCC via f16 MFMA, DCT chunk-linear.
__global__ __launch_bounds__(512, 2) void k_gemm(const float* __restrict__ wav,
                                                 const float* __restrict__ ws,
                                                 u16* __restrict__ mel,
                                                 float* __restrict__ mfcc) {
  extern __shared__ char sm[];  // A: [13 kt][8192 B]; P overlays; db @69632
  const char* Bg = (const char*)(ws + OFF_BG);
  const char* FBc = (const char*)(ws + OFF_FBC);
  const char* DCTc = (const char*)(ws + OFF_DCTC);
  const float* win = ws + OFF_WIN;
  int tid = threadIdx.x, wid = tid >> 6, lane = tid & 63;
  // XCD-chunk swizzle: 512 blocks, 8 XCDs -> 64 consecutive work items per XCD
  int work = (blockIdx.x & 7) * 64 + (blockIdx.x >> 3);
  int b = work >> 3, bx = work & 7;
  const float* wv = wav + (size_t)b * 160000;

  // ---- A build, all 13 ktiles: 4 lanes per frame row (coalesced reads) ----
  {
    int kq = tid & 3, rowq = tid >> 2;
    int frame = bx * 128 + rowq;
    bool fvalid = (frame <= 1000);
#pragma unroll 4
    for (int kt = 0; kt < 13; ++kt) {
      int n0 = kt * 32 + kq * 8;
      int g0 = frame * 160 + n0 - 200;
      float ax[8];
      if (fvalid) {
        if (g0 >= 0 && g0 + 7 < 160000) {
          float4 u = *(const float4*)&wv[g0];
          float4 v = *(const float4*)&wv[g0 + 4];
          ax[0] = u.x; ax[1] = u.y; ax[2] = u.z; ax[3] = u.w;
          ax[4] = v.x; ax[5] = v.y; ax[6] = v.z; ax[7] = v.w;
        } else {
#pragma unroll
          for (int e = 0; e < 8; ++e) ax[e] = wv[reflect_idx(g0 + e)];
        }
      } else {
#pragma unroll
        for (int e = 0; e < 8; ++e) ax[e] = 0.0f;
      }
      float4 w0 = *(const float4*)&win[n0];
      float4 w1 = *(const float4*)&win[n0 + 4];
      uint4 pk;
      pk.x = (u32)f2bf(ax[0] * w0.x) | ((u32)f2bf(ax[1] * w0.y) << 16);
      pk.y = (u32)f2bf(ax[2] * w0.z) | ((u32)f2bf(ax[3] * w0.w) << 16);
      pk.z = (u32)f2bf(ax[4] * w1.x) | ((u32)f2bf(ax[5] * w1.y) << 16);
      pk.w = (u32)f2bf(ax[6] * w1.z) | ((u32)f2bf(ax[7] * w1.w) << 16);
      *(uint4*)(sm + kt * 8192 + kq * 2048 + rowq * 16) = pk;
    }
  }
  __syncthreads();

  // ---- GEMM1: K-loop at unroll-2, 1M x 8N (13 bingroups, bins 0..207) ----
  int NG = (wid < 5) ? 2 : 1;
  int GB = (wid < 5) ? wid * 2 : wid + 5;

  f32x4 acc[8][4];
  const f32x4 zf = {0.0f, 0.0f, 0.0f, 0.0f};
#pragma unroll
  for (int mi = 0; mi < 8; ++mi)
#pragma unroll
    for (int j = 0; j < 4; ++j) acc[mi][j] = zf;

#pragma unroll 2
  for (int kt = 0; kt < 13; ++kt) {
    bf16x8 bfr[4];
    bfr[0] = *(const bf16x8*)(Bg + kt * 32768 + (2 * GB) * 1024 + lane * 16);
    bfr[1] = *(const bf16x8*)(Bg + kt * 32768 + (2 * GB + 1) * 1024 + lane * 16);
    if (NG == 2) {
      bfr[2] = *(const bf16x8*)(Bg + kt * 32768 + (2 * GB + 2) * 1024 + lane * 16);
      bfr[3] = *(const bf16x8*)(Bg + kt * 32768 + (2 * GB + 3) * 1024 + lane * 16);
    }
#pragma unroll
    for (int mi = 0; mi < 8; ++mi) {
      bf16x8 af = *(const bf16x8*)(sm + kt * 8192 + (lane >> 4) * 2048 +
                                   (mi * 16 + (lane & 15)) * 16);
      acc[mi][0] = __builtin_amdgcn_mfma_f32_16x16x32_bf16(af, bfr[0], acc[mi][0], 0, 0, 0);
      acc[mi][1] = __builtin_amdgcn_mfma_f32_16x16x32_bf16(af, bfr[1], acc[mi][1], 0, 0, 0);
      if (NG == 2) {
        acc[mi][2] = __builtin_amdgcn_mfma_f32_16x16x32_bf16(af, bfr[2], acc[mi][2], 0, 0, 0);
        acc[mi][3] = __builtin_amdgcn_mfma_f32_16x16x32_bf16(af, bfr[3], acc[mi][3], 0, 0, 0);
      }
    }
  }
  __syncthreads();  // all A reads done before P overwrites the region

  // ---- P = re^2+im^2 (bf16) @ LDS 0, stride 268; zero bins 208..255 ----
  u16* P = (u16*)sm;  // [128 frame][268]
#pragma unroll
  for (int j = 0; j < 2; ++j) {
    if (j < NG) {
      int bin = (GB + j) * 16 + (lane & 15);
#pragma unroll
      for (int mi = 0; mi < 8; ++mi)
#pragma unroll
        for (int r = 0; r < 4; ++r) {
          int row = mi * 16 + (lane >> 4) * 4 + r;
          float re = acc[mi][2 * j][r], im = acc[mi][2 * j + 1][r];
          P[row * P_STRIDE + bin] = f2bf(re * re + im * im);
        }
    }
  }
  {
    u32* P32 = (u32*)sm;  // zero bins 208..255 (u32 idx 104..127 per row)
    for (int i = tid; i < 3072; i += 512) {
      int row = i / 24, c = i - row * 24;
      P32[row * 134 + 104 + c] = 0;
    }
  }
  __syncthreads();

  // ---- GEMM2 (swapped): D[m][frame] = FB[m][bins] x P^T[bins][frame] ----
  f32x4 macc[4];
#pragma unroll
  for (int nf = 0; nf < 4; ++nf) macc[nf] = zf;
#pragma unroll
  for (int kt = 0; kt < 8; ++kt) {
    int krow = kt * 32 + (lane >> 4) * 8;
    bf16x8 pb = *(const bf16x8*)&P[(wid * 16 + (lane & 15)) * P_STRIDE + krow];
#pragma unroll
    for (int nf = 0; nf < 4; ++nf) {
      bf16x8 fa = *(const bf16x8*)(FBc + (kt * 4 + nf) * 1024 + lane * 16);
      macc[nf] = __builtin_amdgcn_mfma_f32_16x16x32_bf16(fa, pb, macc[nf], 0, 0, 0);
    }
  }

  // ---- mel direct store (bf16): D col = frame, row = m ----
  int t = bx * 128 + wid * 16 + (lane & 15);
  if (t <= 1000) {
#pragma unroll
    for (int nf = 0; nf < 4; ++nf)
#pragma unroll
      for (int r = 0; r < 4; ++r) {
        int m = nf * 16 + (lane >> 4) * 4 + r;
        mel[((size_t)b * 64 + m) * MEL_STRIDE + t] = f2bf(macc[nf][r]);
      }
  }

  // ---- GEMM3 (fused MFCC): db = 10log10(max(mel,1e-10)) -> f16 LDS,
  //      D2[k][t] = DCT16[k][m] x db[t][m]. Wave reads only rows it wrote.
  _Float16* db = (_Float16*)(sm + 69632);  // [128 t][72] f16 (2-way conflicts)
  {
    int tl = wid * 16 + (lane & 15);  // local t row 0..127
#pragma unroll
    for (int nf = 0; nf < 4; ++nf)
#pragma unroll
      for (int r = 0; r < 4; ++r) {
        int m = nf * 16 + (lane >> 4) * 4 + r;
        float d = 10.0f * log10f(fmaxf(macc[nf][r], 1e-10f));
        db[tl * 72 + m] = (_Float16)d;
      }
    f32x4 mf0 = zf, mf1 = zf;
#pragma unroll
    for (int mkt = 0; mkt < 2; ++mkt) {
      int ms = mkt * 32 + (lane >> 4) * 8;
      f16x8 pb3 = *(const f16x8*)&db[(wid * 16 + (lane & 15)) * 72 + ms];
      f16x8 fa0 = *(const f16x8*)(DCTc + (mkt * 2 + 0) * 1024 + lane * 16);
      f16x8 fa1 = *(const f16x8*)(DCTc + (mkt * 2 + 1) * 1024 + lane * 16);
      mf0 = __builtin_amdgcn_mfma_f32_16x16x32_f16(fa0, pb3, mf0, 0, 0, 0);
      mf1 = __builtin_amdgcn_mfma_f32_16x16x32_f16(fa1, pb3, mf1, 0, 0, 0);
    }
    if (t <= 1000) {
#pragma unroll
      for (int r = 0; r < 4; ++r) {
        int k0 = (lane >> 4) * 4 + r;        // 0..15
        mfcc[((size_t)b * 20 + k0) * 1001 + t] = mf0[r];
        int k1 = 16 + (lane >> 4) * 4 + r;   // 16..31, keep <20
        if (k1 < 20)
          mfcc[((size_t)b * 20 + k1) * 1001 + t] = mf1[r];
      }
    }
  }
}

// Wave-parallel EMA scan: one wave per (b,m) row, 16 t/lane (bf16 input),
// affine map compose via shuffle scan. Results bounce through padded LDS
// (stride 17: only free 2-way conflicts) so the global store is cooperative
// and fully coalesced (256 consecutive dwords per instruction) — the direct
// per-lane scalar stores were 4B at 64B stride (16x transaction inflation).
__global__ __launch_bounds__(256) void k_ema(const u16* __restrict__ mel,
                                             float* __restrict__ outp) {
  __shared__ float lb[4][64 * 17];
  int wid = threadIdx.x >> 6, lane = threadIdx.x & 63;
  int row = blockIdx.x * 4 + wid;  // 0..4095
  const u16* src = mel + (size_t)row * MEL_STRIDE + lane * 16;

  float x[16];
  if (lane < 63) {
    uint4 v0 = *(const uint4*)&src[0];  // 8 bf16
    uint4 v1 = *(const uint4*)&src[8];  // 8 bf16
    x[0] = bf2f(v0.x & 0xFFFF);  x[1] = bf2f(v0.x >> 16);
    x[2] = bf2f(v0.y & 0xFFFF);  x[3] = bf2f(v0.y >> 16);
    x[4] = bf2f(v0.z & 0xFFFF);  x[5] = bf2f(v0.z >> 16);
    x[6] = bf2f(v0.w & 0xFFFF);  x[7] = bf2f(v0.w >> 16);
    x[8] = bf2f(v1.x & 0xFFFF);  x[9] = bf2f(v1.x >> 16);
    x[10] = bf2f(v1.y & 0xFFFF); x[11] = bf2f(v1.y >> 16);
    x[12] = bf2f(v1.z & 0xFFFF); x[13] = bf2f(v1.z >> 16);
    x[14] = bf2f(v1.w & 0xFFFF); x[15] = bf2f(v1.w >> 16);
#pragma unroll
    for (int i = 0; i < 16; ++i)
      if (lane * 16 + i > 1000) x[i] = 0.0f;
  } else {
#pragma unroll
    for (int i = 0; i < 16; ++i) x[i] = 0.0f;
  }

  float B = 0.0f;
#pragma unroll
  for (int i = 0; i < 16; ++i) B = fmaf(0.98f, B, 0.02f * x[i]);
  float A = 1.0f;
#pragma unroll
  for (int i = 0; i < 16; ++i) A *= 0.98f;

#pragma unroll
  for (int d = 1; d < 64; d <<= 1) {
    float Ap = __shfl_up(A, d, 64);
    float Bp = __shfl_up(B, d, 64);
    if (lane >= d) {
      B = fmaf(A, Bp, B);
      A = A * Ap;
    }
  }
  float s = __shfl_up(B, 1, 64);
  if (lane == 0) s = 0.0f;

  float* lw = &lb[wid][lane * 17];
#pragma unroll
  for (int i = 0; i < 16; ++i) {
    s = fmaf(0.98f, s, 0.02f * x[i]);
    lw[i] = log1pf(x[i] / (s + 1e-6f));
  }
  __syncthreads();

  // cooperative coalesced store: each instruction writes 256 contiguous dwords
  float* dst = outp + (size_t)row * 1001;
  const float* lr = lb[wid];
  for (int j = lane; j < 1001; j += 64)
    dst[j] = lr[(j >> 4) * 17 + (j & 15)];
}

extern "C" void kernel_launch(void* const* d_in, const int* in_sizes, int n_in,
                              void* d_out, int out_size, void* d_ws, size_t ws_size,
                              hipStream_t stream) {
  const float* wav = (const float*)d_in[0];
  float* out = (float*)d_out;
  float* ws = (float*)d_ws;
  u16* mel = (u16*)(ws + OFF_MEL);

  hipFuncSetAttribute(reinterpret_cast<const void*>(k_gemm),
                      hipFuncAttributeMaxDynamicSharedMemorySize, 106496);

  hipLaunchKernelGGL(k_init, dim3(256), dim3(256), 0, stream, ws);
  hipLaunchKernelGGL(k_gemm, dim3(512), dim3(512), 106496, stream, wav, ws, mel,
                     out + 4100096);
  hipLaunchKernelGGL(k_ema, dim3(1024), dim3(256), 0, stream, mel, out);
}

// Round 28
// 73.444 us; speedup vs baseline: 1.2870x; 1.0042x over previous
//
#include <hip/hip_runtime.h>

#define T_FRAMES 1001
#define MEL_STRIDE 1008
#define P_STRIDE 268

// ws float offsets
#define OFF_WIN 0          // [416] f32
#define OFF_BG  1696       // u16[13 ktile][16384] twiddles, chunked (106496 f)
#define OFF_FBC 108192     // u16 chunked FB: [8 kt][4 nf] chunks x 512 u16 (8192 f)
#define OFF_DCTC 120000    // f16 chunked DCT: [2 mkt][2 q] chunks x 512 f16 (1024 f)
#define OFF_MEL 13748128   // u16(bf16) [4096][1008]

typedef unsigned int u32;
typedef unsigned short u16;
typedef __attribute__((ext_vector_type(8))) short bf16x8;
typedef __attribute__((ext_vector_type(8))) _Float16 f16x8;
typedef __attribute__((ext_vector_type(4))) float f32x4;

__device__ __forceinline__ u16 f2bf(float f) {
  u32 u = __float_as_uint(f);
  u32 r = (u + 0x7FFFu + ((u >> 16) & 1u)) >> 16;
  return (u16)r;
}

__device__ __forceinline__ float bf2f(u32 h) {  // low 16 bits = bf16
  return __uint_as_float(h << 16);
}

__device__ __forceinline__ int reflect_idx(int g) {
  g = (g < 0) ? -g : g;
  g = (g >= 160000) ? (319998 - g) : g;
  return g;
}

__device__ __forceinline__ float melfb(int m, int f) {
  if (f > 200) return 0.0f;
  float freq = 40.0f * (float)f;
  float m_max = 2595.0f * log10f(1.0f + 8000.0f / 700.0f);
  float ms = m_max / 65.0f;
  float fp0 = 700.0f * (powf(10.0f, (float)(m)     * ms / 2595.0f) - 1.0f);
  float fp1 = 700.0f * (powf(10.0f, (float)(m + 1) * ms / 2595.0f) - 1.0f);
  float fp2 = 700.0f * (powf(10.0f, (float)(m + 2) * ms / 2595.0f) - 1.0f);
  float dn = (freq - fp0) / (fp1 - fp0);
  float up = (fp2 - freq) / (fp2 - fp1);
  return fmaxf(0.0f, fminf(dn, up));
}

__global__ __launch_bounds__(256) void k_init(float* __restrict__ ws) {
  float* win = ws + OFF_WIN;
  u16* bg = (u16*)(ws + OFF_BG);
  u16* fbc = (u16*)(ws + OFF_FBC);
  _Float16* dctc = (_Float16*)(ws + OFF_DCTC);
  const float W = 6.28318530717958647692f / 400.0f;
  int tid = blockIdx.x * 256 + threadIdx.x;
  int stride = gridDim.x * 256;
  for (int i = tid; i < 416; i += stride)
    win[i] = (i < 400) ? (0.5f - 0.5f * cosf((float)i * W)) : 0.0f;
  // FB chunked: chunk = kt*4+nf; lane l holds FB[nf*16+(l&15)][kt*32+(l>>4)*8+e]
  for (int i = tid; i < 8 * 4 * 512; i += stride) {
    int chunk = i >> 9, l = (i >> 3) & 63, e = i & 7;
    int kt = chunk >> 2, nf = chunk & 3;
    int m = nf * 16 + (l & 15);
    int f = kt * 32 + (l >> 4) * 8 + e;
    fbc[i] = f2bf(melfb(m, f));
  }
  // DCT chunked: chunk = mkt*2+q; lane l holds DCT[q*16+(l&15)][mkt*32+(l>>4)*8+e]
  for (int i = tid; i < 2 * 2 * 512; i += stride) {
    int chunk = i >> 9, l = (i >> 3) & 63, e = i & 7;
    int mkt = chunk >> 1, q = chunk & 1;
    int k = q * 16 + (l & 15);
    int m = mkt * 32 + (l >> 4) * 8 + e;
    float v = 0.0f;
    if (k < 20) {
      v = cosf(3.14159265358979323846f / 64.0f * ((float)m + 0.5f) * (float)k) * sqrtf(2.0f / 64.0f);
      if (k == 0) v *= 0.70710678118654752440f;
    }
    dctc[i] = (_Float16)v;
  }
  // twiddles, chunked: u16 index = kt*16384 + g*512 + khalf*128 + c15*8 + e
  for (int i = tid; i < 13 * 16384; i += stride) {
    int kt = i >> 14;
    int r = i & 16383;
    int g = r >> 9;
    int khalf = (r >> 7) & 3;
    int c15 = (r >> 3) & 15;
    int e = r & 7;
    int col = g * 16 + c15;
    int n = kt * 32 + khalf * 8 + e;
    int bin = ((col >> 5) << 4) | (col & 15);
    int type = (col >> 4) & 1;
    float v = 0.0f;
    if (n < 400 && bin <= 200) {
      float a = (float)((n * bin) % 400) * W;
      v = type ? -sinf(a) : cosf(a);
    }
    bg[i] = f2bf(v);
  }
}

// One block = 128 frames of one batch row; 512 threads = 8 waves.
// Flat 512-block grid with bijective XCD-chunk swizzle (r26: -4.3us).
// GEMM1: 1M x 8N, dead-column-trimmed, barrier-free K-loop; waves are
// phase-diverse (waves 5-7 carry half the MFMA work), so T5 s_setprio(1)
// around the MFMA cluster lets the CU scheduler favor MFMA-issuing waves
// over load-issuing ones (prereq: role diversity — present here, unlike
// the lockstep GEMM where T5 measured null).
// GEMM2: mel (bf16), FB chunk-linear. GEMM3: fused MFCC, DCT chunk-linear.
__global__ __launch_bounds__(512, 2) void k_gemm(const float* __restrict__ wav,
                                                 const float* __restrict__ ws,
                                                 u16* __restrict__ mel,
                                                 float* __restrict__ mfcc) {
  extern __shared__ char sm[];  // A: [13 kt][8192 B]; P overlays; db @69632
  const char* Bg = (const char*)(ws + OFF_BG);
  const char* FBc = (const char*)(ws + OFF_FBC);
  const char* DCTc = (const char*)(ws + OFF_DCTC);
  const float* win = ws + OFF_WIN;
  int tid = threadIdx.x, wid = tid >> 6, lane = tid & 63;
  // XCD-chunk swizzle: 512 blocks, 8 XCDs -> 64 consecutive work items per XCD
  int work = (blockIdx.x & 7) * 64 + (blockIdx.x >> 3);
  int b = work >> 3, bx = work & 7;
  const float* wv = wav + (size_t)b * 160000;

  // ---- A build, all 13 ktiles: 4 lanes per frame row (coalesced reads) ----
  {
    int kq = tid & 3, rowq = tid >> 2;
    int frame = bx * 128 + rowq;
    bool fvalid = (frame <= 1000);
#pragma unroll 4
    for (int kt = 0; kt < 13; ++kt) {
      int n0 = kt * 32 + kq * 8;
      int g0 = frame * 160 + n0 - 200;
      float ax[8];
      if (fvalid) {
        if (g0 >= 0 && g0 + 7 < 160000) {
          float4 u = *(const float4*)&wv[g0];
          float4 v = *(const float4*)&wv[g0 + 4];
          ax[0] = u.x; ax[1] = u.y; ax[2] = u.z; ax[3] = u.w;
          ax[4] = v.x; ax[5] = v.y; ax[6] = v.z; ax[7] = v.w;
        } else {
#pragma unroll
          for (int e = 0; e < 8; ++e) ax[e] = wv[reflect_idx(g0 + e)];
        }
      } else {
#pragma unroll
        for (int e = 0; e < 8; ++e) ax[e] = 0.0f;
      }
      float4 w0 = *(const float4*)&win[n0];
      float4 w1 = *(const float4*)&win[n0 + 4];
      uint4 pk;
      pk.x = (u32)f2bf(ax[0] * w0.x) | ((u32)f2bf(ax[1] * w0.y) << 16);
      pk.y = (u32)f2bf(ax[2] * w0.z) | ((u32)f2bf(ax[3] * w0.w) << 16);
      pk.z = (u32)f2bf(ax[4] * w1.x) | ((u32)f2bf(ax[5] * w1.y) << 16);
      pk.w = (u32)f2bf(ax[6] * w1.z) | ((u32)f2bf(ax[7] * w1.w) << 16);
      *(uint4*)(sm + kt * 8192 + kq * 2048 + rowq * 16) = pk;
    }
  }
  __syncthreads();

  // ---- GEMM1: K-loop at unroll-2, 1M x 8N (13 bingroups, bins 0..207) ----
  int NG = (wid < 5) ? 2 : 1;
  int GB = (wid < 5) ? wid * 2 : wid + 5;

  f32x4 acc[8][4];
  const f32x4 zf = {0.0f, 0.0f, 0.0f, 0.0f};
#pragma unroll
  for (int mi = 0; mi < 8; ++mi)
#pragma unroll
    for (int j = 0; j < 4; ++j) acc[mi][j] = zf;

#pragma unroll 2
  for (int kt = 0; kt < 13; ++kt) {
    bf16x8 bfr[4];
    bfr[0] = *(const bf16x8*)(Bg + kt * 32768 + (2 * GB) * 1024 + lane * 16);
    bfr[1] = *(const bf16x8*)(Bg + kt * 32768 + (2 * GB + 1) * 1024 + lane * 16);
    if (NG == 2) {
      bfr[2] = *(const bf16x8*)(Bg + kt * 32768 + (2 * GB + 2) * 1024 + lane * 16);
      bfr[3] = *(const bf16x8*)(Bg + kt * 32768 + (2 * GB + 3) * 1024 + lane * 16);
    }
    __builtin_amdgcn_s_setprio(1);
#pragma unroll
    for (int mi = 0; mi < 8; ++mi) {
      bf16x8 af = *(const bf16x8*)(sm + kt * 8192 + (lane >> 4) * 2048 +
                                   (mi * 16 + (lane & 15)) * 16);
      acc[mi][0] = __builtin_amdgcn_mfma_f32_16x16x32_bf16(af, bfr[0], acc[mi][0], 0, 0, 0);
      acc[mi][1] = __builtin_amdgcn_mfma_f32_16x16x32_bf16(af, bfr[1], acc[mi][1], 0, 0, 0);
      if (NG == 2) {
        acc[mi][2] = __builtin_amdgcn_mfma_f32_16x16x32_bf16(af, bfr[2], acc[mi][2], 0, 0, 0);
        acc[mi][3] = __builtin_amdgcn_mfma_f32_16x16x32_bf16(af, bfr[3], acc[mi][3], 0, 0, 0);
      }
    }
    __builtin_amdgcn_s_setprio(0);
  }
  __syncthreads();  // all A reads done before P overwrites the region

  // ---- P = re^2+im^2 (bf16) @ LDS 0, stride 268; zero bins 208..255 ----
  u16* P = (u16*)sm;  // [128 frame][268]
#pragma unroll
  for (int j = 0; j < 2; ++j) {
    if (j < NG) {
      int bin = (GB + j) * 16 + (lane & 15);
#pragma unroll
      for (int mi = 0; mi < 8; ++mi)
#pragma unroll
        for (int r = 0; r < 4; ++r) {
          int row = mi * 16 + (lane >> 4) * 4 + r;
          float re = acc[mi][2 * j][r], im = acc[mi][2 * j + 1][r];
          P[row * P_STRIDE + bin] = f2bf(re * re + im * im);
        }
    }
  }
  {
    u32* P32 = (u32*)sm;  // zero bins 208..255 (u32 idx 104..127 per row)
    for (int i = tid; i < 3072; i += 512) {
      int row = i / 24, c = i - row * 24;
      P32[row * 134 + 104 + c] = 0;
    }
  }
  __syncthreads();

  // ---- GEMM2 (swapped): D[m][frame] = FB[m][bins] x P^T[bins][frame] ----
  f32x4 macc[4];
#pragma unroll
  for (int nf = 0; nf < 4; ++nf) macc[nf] = zf;
#pragma unroll
  for (int kt = 0; kt < 8; ++kt) {
    int krow = kt * 32 + (lane >> 4) * 8;
    bf16x8 pb = *(const bf16x8*)&P[(wid * 16 + (lane & 15)) * P_STRIDE + krow];
#pragma unroll
    for (int nf = 0; nf < 4; ++nf) {
      bf16x8 fa = *(const bf16x8*)(FBc + (kt * 4 + nf) * 1024 + lane * 16);
      macc[nf] = __builtin_amdgcn_mfma_f32_16x16x32_bf16(fa, pb, macc[nf], 0, 0, 0);
    }
  }

  // ---- mel direct store (bf16): D col = frame, row = m ----
  int t = bx * 128 + wid * 16 + (lane & 15);
  if (t <= 1000) {
#pragma unroll
    for (int nf = 0; nf < 4; ++nf)
#pragma unroll
      for (int r = 0; r < 4; ++r) {
        int m = nf * 16 + (lane >> 4) * 4 + r;
        mel[((size_t)b * 64 + m) * MEL_STRIDE + t] = f2bf(macc[nf][r]);
      }
  }

  // ---- GEMM3 (fused MFCC): db = 10log10(max(mel,1e-10)) -> f16 LDS,
  //      D2[k][t] = DCT16[k][m] x db[t][m]. Wave reads only rows it wrote.
  _Float16* db = (_Float16*)(sm + 69632);  // [128 t][72] f16 (2-way conflicts)
  {
    int tl = wid * 16 + (lane & 15);  // local t row 0..127
#pragma unroll
    for (int nf = 0; nf < 4; ++nf)
#pragma unroll
      for (int r = 0; r < 4; ++r) {
        int m = nf * 16 + (lane >> 4) * 4 + r;
        float d = 10.0f * log10f(fmaxf(macc[nf][r], 1e-10f));
        db[tl * 72 + m] = (_Float16)d;
      }
    f32x4 mf0 = zf, mf1 = zf;
#pragma unroll
    for (int mkt = 0; mkt < 2; ++mkt) {
      int ms = mkt * 32 + (lane >> 4) * 8;
      f16x8 pb3 = *(const f16x8*)&db[(wid * 16 + (lane & 15)) * 72 + ms];
      f16x8 fa0 = *(const f16x8*)(DCTc + (mkt * 2 + 0) * 1024 + lane * 16);
      f16x8 fa1 = *(const f16x8*)(DCTc + (mkt * 2 + 1) * 1024 + lane * 16);
      mf0 = __builtin_amdgcn_mfma_f32_16x16x32_f16(fa0, pb3, mf0, 0, 0, 0);
      mf1 = __builtin_amdgcn_mfma_f32_16x16x32_f16(fa1, pb3, mf1, 0, 0, 0);
    }
    if (t <= 1000) {
#pragma unroll
      for (int r = 0; r < 4; ++r) {
        int k0 = (lane >> 4) * 4 + r;        // 0..15
        mfcc[((size_t)b * 20 + k0) * 1001 + t] = mf0[r];
        int k1 = 16 + (lane >> 4) * 4 + r;   // 16..31, keep <20
        if (k1 < 20)
          mfcc[((size_t)b * 20 + k1) * 1001 + t] = mf1[r];
      }
    }
  }
}

// Wave-parallel EMA scan: one wave per (b,m) row, 16 t/lane (bf16 input),
// affine map compose via shuffle scan; coalesced store via padded LDS bounce.
__global__ __launch_bounds__(256) void k_ema(const u16* __restrict__ mel,
                                             float* __restrict__ outp) {
  __shared__ float lb[4][64 * 17];
  int wid = threadIdx.x >> 6, lane = threadIdx.x & 63;
  int row = blockIdx.x * 4 + wid;  // 0..4095
  const u16* src = mel + (size_t)row * MEL_STRIDE + lane * 16;

  float x[16];
  if (lane < 63) {
    uint4 v0 = *(const uint4*)&src[0];  // 8 bf16
    uint4 v1 = *(const uint4*)&src[8];  // 8 bf16
    x[0] = bf2f(v0.x & 0xFFFF);  x[1] = bf2f(v0.x >> 16);
    x[2] = bf2f(v0.y & 0xFFFF);  x[3] = bf2f(v0.y >> 16);
    x[4] = bf2f(v0.z & 0xFFFF);  x[5] = bf2f(v0.z >> 16);
    x[6] = bf2f(v0.w & 0xFFFF);  x[7] = bf2f(v0.w >> 16);
    x[8] = bf2f(v1.x & 0xFFFF);  x[9] = bf2f(v1.x >> 16);
    x[10] = bf2f(v1.y & 0xFFFF); x[11] = bf2f(v1.y >> 16);
    x[12] = bf2f(v1.z & 0xFFFF); x[13] = bf2f(v1.z >> 16);
    x[14] = bf2f(v1.w & 0xFFFF); x[15] = bf2f(v1.w >> 16);
#pragma unroll
    for (int i = 0; i < 16; ++i)
      if (lane * 16 + i > 1000) x[i] = 0.0f;
  } else {
#pragma unroll
    for (int i = 0; i < 16; ++i) x[i] = 0.0f;
  }

  float B = 0.0f;
#pragma unroll
  for (int i = 0; i < 16; ++i) B = fmaf(0.98f, B, 0.02f * x[i]);
  float A = 1.0f;
#pragma unroll
  for (int i = 0; i < 16; ++i) A *= 0.98f;

#pragma unroll
  for (int d = 1; d < 64; d <<= 1) {
    float Ap = __shfl_up(A, d, 64);
    float Bp = __shfl_up(B, d, 64);
    if (lane >= d) {
      B = fmaf(A, Bp, B);
      A = A * Ap;
    }
  }
  float s = __shfl_up(B, 1, 64);
  if (lane == 0) s = 0.0f;

  float* lw = &lb[wid][lane * 17];
#pragma unroll
  for (int i = 0; i < 16; ++i) {
    s = fmaf(0.98f, s, 0.02f * x[i]);
    lw[i] = log1pf(x[i] / (s + 1e-6f));
  }
  __syncthreads();

  // cooperative coalesced store: each instruction writes 256 contiguous dwords
  float* dst = outp + (size_t)row * 1001;
  const float* lr = lb[wid];
  for (int j = lane; j < 1001; j += 64)
    dst[j] = lr[(j >> 4) * 17 + (j & 15)];
}

extern "C" void kernel_launch(void* const* d_in, const int* in_sizes, int n_in,
                              void* d_out, int out_size, void* d_ws, size_t ws_size,
                              hipStream_t stream) {
  const float* wav = (const float*)d_in[0];
  float* out = (float*)d_out;
  float* ws = (float*)d_ws;
  u16* mel = (u16*)(ws + OFF_MEL);

  hipFuncSetAttribute(reinterpret_cast<const void*>(k_gemm),
                      hipFuncAttributeMaxDynamicSharedMemorySize, 106496);

  hipLaunchKernelGGL(k_init, dim3(256), dim3(256), 0, stream, ws);
  hipLaunchKernelGGL(k_gemm, dim3(512), dim3(512), 106496, stream, wav, ws, mel,
                     out + 4100096);
  hipLaunchKernelGGL(k_ema, dim3(1024), dim3(256), 0, stream, mel, out);
}